// Round 10
// baseline (496.159 us; speedup 1.0000x reference)
//
#include <hip/hip_runtime.h>
#include <stdint.h>

#define NB 4
#define NH 8
#define SS 2048
#define EE 512
#define DD 64
#define MM (NB*SS)      // 8192

typedef __attribute__((ext_vector_type(8))) __bf16 bf16x8;
typedef __attribute__((ext_vector_type(8))) unsigned short ushort8;
typedef __attribute__((ext_vector_type(4))) unsigned short ushort4v;
typedef __attribute__((ext_vector_type(4))) float f32x4;

__device__ __forceinline__ uint16_t f2bf(float f) {
    union { float f; uint32_t u; } v; v.f = f;
    return (uint16_t)((v.u + 0x7fffu + ((v.u >> 16) & 1u)) >> 16);   // RNE
}
__device__ __forceinline__ float bf2f(uint16_t h) {
    union { uint32_t u; float f; } v; v.u = ((uint32_t)h) << 16;
    return v.f;
}

// ---------------- merged split: x + Wq/Wk/Wv/Wo -> bf16 hi/lo ----------------
__global__ __launch_bounds__(256) void split_all(
        const float* __restrict__ x,  const float* __restrict__ Wq,
        const float* __restrict__ Wk, const float* __restrict__ Wv,
        const float* __restrict__ Wo,
        uint16_t* __restrict__ xh, uint16_t* __restrict__ xl,
        uint16_t* __restrict__ wqkvh, uint16_t* __restrict__ wqkvl,
        uint16_t* __restrict__ woh, uint16_t* __restrict__ wol)
{
    const int tid = threadIdx.x;
    int b = blockIdx.x;
    const float* src; uint16_t* dh; uint16_t* dl; int i;
    if (b < 4096) { src = x; dh = xh; dl = xl; i = b*256 + tid; }
    else {
        b -= 4096;
        const int seg = b >> 8;                 // 0..3
        i = (b & 255)*256 + tid;
        src = (seg == 0) ? Wq : (seg == 1) ? Wk : (seg == 2) ? Wv : Wo;
        if (seg < 3) { dh = wqkvh + (size_t)seg*262144; dl = wqkvl + (size_t)seg*262144; }
        else         { dh = woh; dl = wol; }
    }
    f32x4 v = reinterpret_cast<const f32x4*>(src)[i];
    ushort4v h, l;
#pragma unroll
    for (int j = 0; j < 4; j++) {
        uint16_t hh = f2bf(v[j]);
        h[j] = hh;
        l[j] = f2bf(v[j] - bf2f(hh));
    }
    reinterpret_cast<ushort4v*>(dh)[i] = h;
    reinterpret_cast<ushort4v*>(dl)[i] = l;
}

// ---------------- merged QKV projection, BM=64, swizzled LDS (3 blocks/CU) ----------------
__global__ __launch_bounds__(256, 3)
void gemm_qkv(const uint16_t* __restrict__ Ah, const uint16_t* __restrict__ Al,
              const uint16_t* __restrict__ Bh, const uint16_t* __restrict__ Bl,
              const float* __restrict__ bq, const float* __restrict__ bk,
              const float* __restrict__ bv, float qscale,
              uint16_t* __restrict__ qh, uint16_t* __restrict__ ql,
              uint16_t* __restrict__ kh, uint16_t* __restrict__ kl,
              uint16_t* __restrict__ vh)
{
    __shared__ uint16_t sAh[64*64], sAl[64*64], sBh[128*64], sBl[128*64];
    const int t = threadIdx.x;
    const int lane = t & 63;
    const int wave = t >> 6;
    const int m0 = blockIdx.x * 64;
    const int n0 = blockIdx.y * 128;

    f32x4 zero = {0.f, 0.f, 0.f, 0.f};
    f32x4 acc[2][4];
#pragma unroll
    for (int i = 0; i < 2; i++)
#pragma unroll
        for (int j = 0; j < 4; j++) acc[i][j] = zero;

    const int sr = t >> 3;        // 0..31
    const int c8 = t & 7;         // source chunk
    const int sc = c8 * 8;
    const int dsw = ((c8 ^ (sr & 7)) << 3);   // swizzled dest chunk offset
    const int l15 = lane & 15;
    const int l16 = lane >> 4;

    for (int k0 = 0; k0 < EE; k0 += 64) {
#pragma unroll
        for (int p = 0; p < 2; p++) {
            const int row = sr + 32 * p;
            const size_t ga = (size_t)(m0 + row) * EE + k0 + sc;
            const int o = row*64 + dsw;
            *reinterpret_cast<ushort8*>(&sAh[o]) = *reinterpret_cast<const ushort8*>(&Ah[ga]);
            *reinterpret_cast<ushort8*>(&sAl[o]) = *reinterpret_cast<const ushort8*>(&Al[ga]);
        }
#pragma unroll
        for (int p = 0; p < 4; p++) {
            const int row = sr + 32 * p;
            const size_t gb = (size_t)(n0 + row) * EE + k0 + sc;
            const int o = row*64 + dsw;
            *reinterpret_cast<ushort8*>(&sBh[o]) = *reinterpret_cast<const ushort8*>(&Bh[gb]);
            *reinterpret_cast<ushort8*>(&sBl[o]) = *reinterpret_cast<const ushort8*>(&Bl[gb]);
        }
        __syncthreads();
        const int mw = (wave >> 1) * 32;
        const int nw = (wave & 1) * 64;
#pragma unroll
        for (int ks = 0; ks < 2; ks++) {
            const int kc = ks*4 + l16;
            bf16x8 fah[2], fal[2], fbh[4], fbl[4];
#pragma unroll
            for (int i = 0; i < 2; i++) {
                const int ar = mw + 16*i + l15;
                const int ra = ar*64 + ((kc ^ (ar & 7)) << 3);
                fah[i] = *reinterpret_cast<const bf16x8*>(&sAh[ra]);
                fal[i] = *reinterpret_cast<const bf16x8*>(&sAl[ra]);
            }
#pragma unroll
            for (int j = 0; j < 4; j++) {
                const int br = nw + 16*j + l15;
                const int rb = br*64 + ((kc ^ (br & 7)) << 3);
                fbh[j] = *reinterpret_cast<const bf16x8*>(&sBh[rb]);
                fbl[j] = *reinterpret_cast<const bf16x8*>(&sBl[rb]);
            }
#pragma unroll
            for (int i = 0; i < 2; i++)
#pragma unroll
                for (int j = 0; j < 4; j++) {
                    acc[i][j] = __builtin_amdgcn_mfma_f32_16x16x32_bf16(fah[i], fbh[j], acc[i][j], 0, 0, 0);
                    acc[i][j] = __builtin_amdgcn_mfma_f32_16x16x32_bf16(fah[i], fbl[j], acc[i][j], 0, 0, 0);
                    acc[i][j] = __builtin_amdgcn_mfma_f32_16x16x32_bf16(fal[i], fbh[j], acc[i][j], 0, 0, 0);
                }
        }
        __syncthreads();
    }

    const int mw = (wave >> 1) * 32;
    const int nw = (wave & 1) * 64;
#pragma unroll
    for (int j = 0; j < 4; j++) {
        const int col = n0 + nw + 16*j + l15;            // 0..1535
        const int seg = col >> 9;                        // 0=Q 1=K 2=V
        const int c   = col & 511;
        const float bias = (seg == 0 ? bq : (seg == 1 ? bk : bv))[c];
        const float scale = (seg == 0) ? qscale : 1.0f;
        const int h = c >> 6, d = c & 63;
#pragma unroll
        for (int i = 0; i < 2; i++) {
            const int rowb = m0 + mw + 16*i + (l16 << 2);
#pragma unroll
            for (int r4 = 0; r4 < 4; r4++) {
                const int m = rowb + r4;
                const float val = (acc[i][j][r4] + bias) * scale;
                const int bb = m >> 11, s = m & (SS-1);
                const size_t idx = (((size_t)(bb*NH + h)) * SS + s) * DD + d;
                const uint16_t hi = f2bf(val);
                if (seg == 0)      { qh[idx] = hi; ql[idx] = f2bf(val - bf2f(hi)); }
                else if (seg == 1) { kh[idx] = hi; kl[idx] = f2bf(val - bf2f(hi)); }
                else               { vh[idx] = hi; }
            }
        }
    }
}

// ---------------- out-projection, BM=64, swizzled LDS (3 blocks/CU) ----------------
__global__ __launch_bounds__(256, 3)
void gemm_out(const uint16_t* __restrict__ Ah, const uint16_t* __restrict__ Al,
              const uint16_t* __restrict__ Bh, const uint16_t* __restrict__ Bl,
              const float* __restrict__ bo, float* __restrict__ Of)
{
    __shared__ uint16_t sAh[64*64], sAl[64*64], sBh[128*64], sBl[128*64];
    const int t = threadIdx.x;
    const int lane = t & 63;
    const int wave = t >> 6;
    const int m0 = blockIdx.x * 64;
    const int n0 = blockIdx.y * 128;

    f32x4 zero = {0.f, 0.f, 0.f, 0.f};
    f32x4 acc[2][4];
#pragma unroll
    for (int i = 0; i < 2; i++)
#pragma unroll
        for (int j = 0; j < 4; j++) acc[i][j] = zero;

    const int sr = t >> 3;
    const int c8 = t & 7;
    const int sc = c8 * 8;
    const int dsw = ((c8 ^ (sr & 7)) << 3);
    const int l15 = lane & 15;
    const int l16 = lane >> 4;

    for (int k0 = 0; k0 < EE; k0 += 64) {
#pragma unroll
        for (int p = 0; p < 2; p++) {
            const int row = sr + 32 * p;
            const size_t ga = (size_t)(m0 + row) * EE + k0 + sc;
            const int o = row*64 + dsw;
            *reinterpret_cast<ushort8*>(&sAh[o]) = *reinterpret_cast<const ushort8*>(&Ah[ga]);
            *reinterpret_cast<ushort8*>(&sAl[o]) = *reinterpret_cast<const ushort8*>(&Al[ga]);
        }
#pragma unroll
        for (int p = 0; p < 4; p++) {
            const int row = sr + 32 * p;
            const size_t gb = (size_t)(n0 + row) * EE + k0 + sc;
            const int o = row*64 + dsw;
            *reinterpret_cast<ushort8*>(&sBh[o]) = *reinterpret_cast<const ushort8*>(&Bh[gb]);
            *reinterpret_cast<ushort8*>(&sBl[o]) = *reinterpret_cast<const ushort8*>(&Bl[gb]);
        }
        __syncthreads();
        const int mw = (wave >> 1) * 32;
        const int nw = (wave & 1) * 64;
#pragma unroll
        for (int ks = 0; ks < 2; ks++) {
            const int kc = ks*4 + l16;
            bf16x8 fah[2], fal[2], fbh[4], fbl[4];
#pragma unroll
            for (int i = 0; i < 2; i++) {
                const int ar = mw + 16*i + l15;
                const int ra = ar*64 + ((kc ^ (ar & 7)) << 3);
                fah[i] = *reinterpret_cast<const bf16x8*>(&sAh[ra]);
                fal[i] = *reinterpret_cast<const bf16x8*>(&sAl[ra]);
            }
#pragma unroll
            for (int j = 0; j < 4; j++) {
                const int br = nw + 16*j + l15;
                const int rb = br*64 + ((kc ^ (br & 7)) << 3);
                fbh[j] = *reinterpret_cast<const bf16x8*>(&sBh[rb]);
                fbl[j] = *reinterpret_cast<const bf16x8*>(&sBl[rb]);
            }
#pragma unroll
            for (int i = 0; i < 2; i++)
#pragma unroll
                for (int j = 0; j < 4; j++) {
                    acc[i][j] = __builtin_amdgcn_mfma_f32_16x16x32_bf16(fah[i], fbh[j], acc[i][j], 0, 0, 0);
                    acc[i][j] = __builtin_amdgcn_mfma_f32_16x16x32_bf16(fah[i], fbl[j], acc[i][j], 0, 0, 0);
                    acc[i][j] = __builtin_amdgcn_mfma_f32_16x16x32_bf16(fal[i], fbh[j], acc[i][j], 0, 0, 0);
                }
        }
        __syncthreads();
    }

    const int mw = (wave >> 1) * 32;
    const int nw = (wave & 1) * 64;
#pragma unroll
    for (int j = 0; j < 4; j++) {
        const int col = n0 + nw + 16*j + l15;
        const float bv = bo[col];
#pragma unroll
        for (int i = 0; i < 2; i++) {
            const int rowb = m0 + mw + 16*i + (l16 << 2);
#pragma unroll
            for (int r4 = 0; r4 < 4; r4++)
                Of[(size_t)(rowb + r4) * EE + col] = acc[i][j][r4] + bv;
        }
    }
}

// ---------------- fused flash attention, sum-only softmax, 3-barrier phase 2 ----------------
// LDS (81920 B total, 2 blocks/CU), all regions XOR-swizzled (chunk ^= row&7):
//   K region @0      : 32768 B = phase1 hi-dbuf (2 x 16384) | phase2 hi @0 + lo @+8192 elems
//   W region @16384  : 32768 B = [128][128] bf16 weights tile
//   V region @32768  : 16384 B = [64][128] bf16 V^T tile
__global__ __launch_bounds__(256, 2)
void attn_fused(const uint16_t* __restrict__ Qh, const uint16_t* __restrict__ Ql,
                const uint16_t* __restrict__ Kh, const uint16_t* __restrict__ Kl,
                const uint16_t* __restrict__ Vh,
                float* __restrict__ attn,
                uint16_t* __restrict__ Oh, uint16_t* __restrict__ Ol)
{
    __shared__ __align__(16) uint16_t smem[40960];   // 81920 B
    uint16_t* kreg = smem;
    uint16_t* wlds = smem + 16384;
    uint16_t* vlds = smem + 32768;

    const int t = threadIdx.x, lane = t & 63, wave = t >> 6;
    const int qt = blockIdx.x, bh = blockIdx.y;
    const size_t hb = (size_t)bh * SS * DD;
    const uint16_t* kbh = Kh + hb;
    const uint16_t* kbl = Kl + hb;
    const uint16_t* vbs = Vh + hb;

    const int l15 = lane & 15;
    const int l16 = lane >> 4;
    const int sr = t >> 3;        // 0..31
    const int c8 = t & 7;
    const int sc = c8 * 8;
    const int dsw = ((c8 ^ (sr & 7)) << 3);

    // ---- K staging regs (global->reg->LDS, swizzled dest) ----
    ushort8 krh[4], krl[4];
    auto kload_hi = [&](int kt) {
#pragma unroll
        for (int p = 0; p < 4; p++)
            krh[p] = *reinterpret_cast<const ushort8*>(&kbh[(size_t)(kt*128 + sr + 32*p) * DD + sc]);
    };
    auto kwrite_hi = [&](uint16_t* buf) {
#pragma unroll
        for (int p = 0; p < 4; p++)
            *reinterpret_cast<ushort8*>(&buf[(sr + 32*p)*64 + dsw]) = krh[p];
    };
    auto kload = [&](int kt) {
#pragma unroll
        for (int p = 0; p < 4; p++) {
            const size_t g = (size_t)(kt*128 + sr + 32*p) * DD + sc;
            krh[p] = *reinterpret_cast<const ushort8*>(&kbh[g]);
            krl[p] = *reinterpret_cast<const ushort8*>(&kbl[g]);
        }
    };
    auto kwrite = [&]() {
#pragma unroll
        for (int p = 0; p < 4; p++) {
            const int o = (sr + 32*p)*64 + dsw;
            *reinterpret_cast<ushort8*>(&kreg[o]) = krh[p];
            *reinterpret_cast<ushort8*>(&kreg[8192 + o]) = krl[p];
        }
    };

    // ---- Q fragments in registers (persistent) ----
    bf16x8 qfh[2][2], qfl[2][2];
#pragma unroll
    for (int i = 0; i < 2; i++)
#pragma unroll
        for (int ks = 0; ks < 2; ks++) {
            const size_t qa = hb + (size_t)(qt*128 + wave*32 + 16*i + l15) * DD + ks*32 + l16*8;
            qfh[i][ks] = *reinterpret_cast<const bf16x8*>(&Qh[qa]);
            qfl[i][ks] = *reinterpret_cast<const bf16x8*>(&Ql[qa]);
        }

    f32x4 zero = {0.f, 0.f, 0.f, 0.f};
    f32x4 lsum[2] = {zero, zero};

    // ================= phase 1: row sums of exp2(scores), single-pass bf16 =================
    kload_hi(0);
#pragma unroll 1
    for (int kt = 0; kt < 16; kt++) {
        uint16_t* buf = kreg + (kt & 1) * 8192;
        kwrite_hi(buf);
        if (kt < 15) kload_hi(kt + 1);
        __syncthreads();

        f32x4 accs[2][8];
#pragma unroll
        for (int i = 0; i < 2; i++)
#pragma unroll
            for (int j = 0; j < 8; j++) accs[i][j] = zero;

#pragma unroll
        for (int ks = 0; ks < 2; ks++) {
            const int kc = ks*4 + l16;
#pragma unroll
            for (int j = 0; j < 8; j++) {
                const int kr = 16*j + l15;
                bf16x8 fbh = *reinterpret_cast<const bf16x8*>(&buf[kr*64 + ((kc ^ (kr & 7)) << 3)]);
#pragma unroll
                for (int i = 0; i < 2; i++)
                    accs[i][j] = __builtin_amdgcn_mfma_f32_16x16x32_bf16(qfh[i][ks], fbh, accs[i][j], 0, 0, 0);
            }
        }

#pragma unroll
        for (int i = 0; i < 2; i++)
#pragma unroll
            for (int j = 0; j < 8; j++)
#pragma unroll
                for (int r = 0; r < 4; r++)
                    lsum[i][r] += __builtin_amdgcn_exp2f(accs[i][j][r]);
    }

    // finalize: reduce over the 16-lane row group, invert
    f32x4 iv[2];
#pragma unroll
    for (int i = 0; i < 2; i++)
#pragma unroll
        for (int r = 0; r < 4; r++) {
            float s = lsum[i][r];
#pragma unroll
            for (int o = 1; o < 16; o <<= 1) s += __shfl_xor(s, o);
            iv[i][r] = 1.0f / s;
        }

    f32x4 acco[2][4];
#pragma unroll
    for (int i = 0; i < 2; i++)
#pragma unroll
        for (int j = 0; j < 4; j++) acco[i][j] = zero;

    float* wbase = attn + ((size_t)bh * SS + qt*128) * SS;

    // ---- V staging: pair-packed b32 writes, swizzled ----
    const int pk = t & 63;             // k-pair index (k = 2pk, 2pk+1)
    const int dbase = (t >> 6) * 16;   // d-quarter
    ushort8 vr[2][2];
    auto vload = [&](int kt) {
#pragma unroll
        for (int u = 0; u < 2; u++)
#pragma unroll
            for (int s = 0; s < 2; s++)
                vr[u][s] = *reinterpret_cast<const ushort8*>(
                    &vbs[(size_t)(kt*128 + 2*pk + s) * DD + dbase + u*8]);
    };
    auto vwrite = [&]() {
#pragma unroll
        for (int u = 0; u < 2; u++)
#pragma unroll
            for (int e = 0; e < 8; e++) {
                const int d = dbase + u*8 + e;
                const int off = d*128 + (((pk >> 2) ^ (d & 7)) << 3) + 2*(pk & 3);
                const uint32_t pack = (uint32_t)(unsigned short)vr[u][0][e]
                                    | ((uint32_t)(unsigned short)vr[u][1][e] << 16);
                *reinterpret_cast<uint32_t*>(&vlds[off]) = pack;
            }
    };

    __syncthreads();   // phase boundary: all phase-1 reads of K region done

    // ================= phase 2: recompute (3-pass), write weights, PV =================
    kload(0); vload(0);
#pragma unroll 1
    for (int kt = 0; kt < 16; kt++) {
        kwrite();
        vwrite();
        __syncthreads();                       // bar1: K/V staged

        f32x4 accs[2][8];
#pragma unroll
        for (int i = 0; i < 2; i++)
#pragma unroll
            for (int j = 0; j < 8; j++) accs[i][j] = zero;
#pragma unroll
        for (int ks = 0; ks < 2; ks++) {
            const int kc = ks*4 + l16;
#pragma unroll
            for (int j = 0; j < 8; j++) {
                const int kr = 16*j + l15;
                const int rb = kr*64 + ((kc ^ (kr & 7)) << 3);
                bf16x8 fbh = *reinterpret_cast<const bf16x8*>(&kreg[rb]);
                bf16x8 fbl = *reinterpret_cast<const bf16x8*>(&kreg[8192 + rb]);
#pragma unroll
                for (int i = 0; i < 2; i++) {
                    accs[i][j] = __builtin_amdgcn_mfma_f32_16x16x32_bf16(qfh[i][ks], fbh, accs[i][j], 0, 0, 0);
                    accs[i][j] = __builtin_amdgcn_mfma_f32_16x16x32_bf16(qfh[i][ks], fbl, accs[i][j], 0, 0, 0);
                    accs[i][j] = __builtin_amdgcn_mfma_f32_16x16x32_bf16(qfl[i][ks], fbh, accs[i][j], 0, 0, 0);
                }
            }
        }

        // prefetch next tile's K/V while VALU works
        if (kt < 15) { kload(kt + 1); vload(kt + 1); }

        // normalize: w = exp2(s) * inv_sum
#pragma unroll
        for (int i = 0; i < 2; i++)
#pragma unroll
            for (int j = 0; j < 8; j++)
#pragma unroll
                for (int r = 0; r < 4; r++)
                    accs[i][j][r] = __builtin_amdgcn_exp2f(accs[i][j][r]) * iv[i][r];

        // W bf16 -> dedicated swizzled region (prev PV finished before bar1)
#pragma unroll
        for (int i = 0; i < 2; i++)
#pragma unroll
            for (int r = 0; r < 4; r++) {
                const int row = wave*32 + 16*i + l16*4 + r;
                const int rm = row & 7;
#pragma unroll
                for (int j = 0; j < 8; j++) {
                    const int off = row*128 + ((((2*j + (l15 >> 3)) ^ rm)) << 3) + (l15 & 7);
                    wlds[off] = f2bf(accs[i][j][r]);
                }
            }
        __syncthreads();                       // bar2: W visible

        // weight stores issued here: PV MFMA below hides the store latency
#pragma unroll
        for (int i = 0; i < 2; i++)
#pragma unroll
            for (int r = 0; r < 4; r++) {
                const int row = wave*32 + 16*i + l16*4 + r;
                float* wout = wbase + (size_t)row * SS + kt*128 + l15;
#pragma unroll
                for (int j = 0; j < 8; j++) wout[16*j] = accs[i][j][r];
            }

        // PV: O += W @ V
#pragma unroll
        for (int ks = 0; ks < 4; ks++) {
            const int kc = ks*4 + l16;
            bf16x8 wa[2], vbf[4];
#pragma unroll
            for (int i = 0; i < 2; i++) {
                const int row = wave*32 + 16*i + l15;
                wa[i] = *reinterpret_cast<const bf16x8*>(&wlds[row*128 + ((kc ^ (row & 7)) << 3)]);
            }
#pragma unroll
            for (int j = 0; j < 4; j++) {
                const int d = 16*j + l15;
                vbf[j] = *reinterpret_cast<const bf16x8*>(&vlds[d*128 + ((kc ^ (d & 7)) << 3)]);
            }
#pragma unroll
            for (int i = 0; i < 2; i++)
#pragma unroll
                for (int j = 0; j < 4; j++)
                    acco[i][j] = __builtin_amdgcn_mfma_f32_16x16x32_bf16(wa[i], vbf[j], acco[i][j], 0, 0, 0);
        }
        __syncthreads();                       // bar3: PV reads done; stores drain
    }

    // epilogue: attn_output split-bf16 into [b, s, h*64+d]
    const int b = bh >> 3, h = bh & 7;
#pragma unroll
    for (int i = 0; i < 2; i++)
#pragma unroll
        for (int j = 0; j < 4; j++)
#pragma unroll
            for (int r4 = 0; r4 < 4; r4++) {
                const int srow = qt*128 + wave*32 + 16*i + (l16 << 2) + r4;
                const int col = h*64 + 16*j + l15;
                const size_t idx = ((size_t)b * SS + srow) * (size_t)EE + col;
                const float val = acco[i][j][r4];
                const uint16_t hh = f2bf(val);
                Oh[idx] = hh;
                Ol[idx] = f2bf(val - bf2f(hh));
            }
}

extern "C" void kernel_launch(void* const* d_in, const int* in_sizes, int n_in,
                              void* d_out, int out_size, void* d_ws, size_t ws_size,
                              hipStream_t stream)
{
    const float* x  = (const float*)d_in[0];
    const float* Wq = (const float*)d_in[1];
    const float* bq = (const float*)d_in[2];
    const float* Wk = (const float*)d_in[3];
    const float* bk = (const float*)d_in[4];
    const float* Wv = (const float*)d_in[5];
    const float* bv = (const float*)d_in[6];
    const float* Wo = (const float*)d_in[7];
    const float* bo = (const float*)d_in[8];

    float* outF = (float*)d_out;
    float* attn = outF + (size_t)MM * EE;   // output 1 region (normalized weights)

    const size_t NXE = (size_t)MM * EE;     // 4,194,304
    const size_t NW  = (size_t)EE * EE;     // 262,144
    uint16_t* p = (uint16_t*)d_ws;
    uint16_t* xh    = p;          p += NXE;
    uint16_t* xl    = p;          p += NXE;
    uint16_t* wqkvh = p;          p += 3*NW;
    uint16_t* wqkvl = p;          p += 3*NW;
    uint16_t* woh   = p;          p += NW;
    uint16_t* wol   = p;          p += NW;
    uint16_t* qh    = p;          p += NXE;
    uint16_t* ql    = p;          p += NXE;
    uint16_t* kh    = p;          p += NXE;
    uint16_t* kl    = p;          p += NXE;
    uint16_t* vh    = p;          p += NXE;
    uint16_t* ah    = p;          p += NXE;
    uint16_t* al    = p;          p += NXE;

    split_all<<<4096 + 4*256, 256, 0, stream>>>(x, Wq, Wk, Wv, Wo,
                                                xh, xl, wqkvh, wqkvl, woh, wol);

    // Q scaled by 0.125*log2(e): scores land in log2 units -> softmax uses exp2 directly
    const float qscale = 0.125f * 1.44269504088896340736f;
    gemm_qkv<<<dim3(MM/64, (3*EE)/128), 256, 0, stream>>>(
        xh, xl, wqkvh, wqkvl, bq, bk, bv, qscale, qh, ql, kh, kl, vh);

    attn_fused<<<dim3(SS/128, NB*NH), 256, 0, stream>>>(qh, ql, kh, kl, vh, attn, ah, al);

    gemm_out<<<dim3(MM/64, EE/128), 256, 0, stream>>>(ah, al, woh, wol, bo, outF);
}

// Round 11
// 249.927 us; speedup vs baseline: 1.9852x; 1.9852x over previous
//
#include <hip/hip_runtime.h>
#include <stdint.h>

#define NB 4
#define NH 8
#define SS 2048
#define EE 512
#define DD 64
#define MM (NB*SS)      // 8192
#define LDP 72          // padded LDS row (bf16 elems) for K-dim-64 tiles (attn)
#define LDW 136         // padded LDS row for 128-wide W / V^T tiles (attn)

typedef __attribute__((ext_vector_type(8))) __bf16 bf16x8;
typedef __attribute__((ext_vector_type(8))) unsigned short ushort8;
typedef __attribute__((ext_vector_type(4))) unsigned short ushort4v;
typedef __attribute__((ext_vector_type(4))) float f32x4;

__device__ __forceinline__ uint16_t f2bf(float f) {
    union { float f; uint32_t u; } v; v.f = f;
    return (uint16_t)((v.u + 0x7fffu + ((v.u >> 16) & 1u)) >> 16);   // RNE
}
__device__ __forceinline__ float bf2f(uint16_t h) {
    union { uint32_t u; float f; } v; v.u = ((uint32_t)h) << 16;
    return v.f;
}

// ---------------- merged split: x + Wq/Wk/Wv/Wo -> bf16 hi/lo ----------------
__global__ __launch_bounds__(256) void split_all(
        const float* __restrict__ x,  const float* __restrict__ Wq,
        const float* __restrict__ Wk, const float* __restrict__ Wv,
        const float* __restrict__ Wo,
        uint16_t* __restrict__ xh, uint16_t* __restrict__ xl,
        uint16_t* __restrict__ wqkvh, uint16_t* __restrict__ wqkvl,
        uint16_t* __restrict__ woh, uint16_t* __restrict__ wol)
{
    const int tid = threadIdx.x;
    int b = blockIdx.x;
    const float* src; uint16_t* dh; uint16_t* dl; int i;
    if (b < 4096) { src = x; dh = xh; dl = xl; i = b*256 + tid; }
    else {
        b -= 4096;
        const int seg = b >> 8;                 // 0..3
        i = (b & 255)*256 + tid;
        src = (seg == 0) ? Wq : (seg == 1) ? Wk : (seg == 2) ? Wv : Wo;
        if (seg < 3) { dh = wqkvh + (size_t)seg*262144; dl = wqkvl + (size_t)seg*262144; }
        else         { dh = woh; dl = wol; }
    }
    f32x4 v = reinterpret_cast<const f32x4*>(src)[i];
    ushort4v h, l;
#pragma unroll
    for (int j = 0; j < 4; j++) {
        uint16_t hh = f2bf(v[j]);
        h[j] = hh;
        l[j] = f2bf(v[j] - bf2f(hh));
    }
    reinterpret_cast<ushort4v*>(dh)[i] = h;
    reinterpret_cast<ushort4v*>(dl)[i] = l;
}

// ---------------- merged QKV projection, BM=64, swizzled LDS (3 blocks/CU) ----------------
__global__ __launch_bounds__(256, 3)
void gemm_qkv(const uint16_t* __restrict__ Ah, const uint16_t* __restrict__ Al,
              const uint16_t* __restrict__ Bh, const uint16_t* __restrict__ Bl,
              const float* __restrict__ bq, const float* __restrict__ bk,
              const float* __restrict__ bv, float qscale,
              uint16_t* __restrict__ qh, uint16_t* __restrict__ ql,
              uint16_t* __restrict__ kh, uint16_t* __restrict__ kl,
              uint16_t* __restrict__ vh)
{
    __shared__ uint16_t sAh[64*64], sAl[64*64], sBh[128*64], sBl[128*64];
    const int t = threadIdx.x;
    const int lane = t & 63;
    const int wave = t >> 6;
    const int m0 = blockIdx.x * 64;
    const int n0 = blockIdx.y * 128;

    f32x4 zero = {0.f, 0.f, 0.f, 0.f};
    f32x4 acc[2][4];
#pragma unroll
    for (int i = 0; i < 2; i++)
#pragma unroll
        for (int j = 0; j < 4; j++) acc[i][j] = zero;

    const int sr = t >> 3;        // 0..31
    const int c8 = t & 7;         // source chunk
    const int sc = c8 * 8;
    const int dsw = ((c8 ^ (sr & 7)) << 3);   // swizzled dest chunk offset
    const int l15 = lane & 15;
    const int l16 = lane >> 4;

    for (int k0 = 0; k0 < EE; k0 += 64) {
#pragma unroll
        for (int p = 0; p < 2; p++) {
            const int row = sr + 32 * p;
            const size_t ga = (size_t)(m0 + row) * EE + k0 + sc;
            const int o = row*64 + dsw;
            *reinterpret_cast<ushort8*>(&sAh[o]) = *reinterpret_cast<const ushort8*>(&Ah[ga]);
            *reinterpret_cast<ushort8*>(&sAl[o]) = *reinterpret_cast<const ushort8*>(&Al[ga]);
        }
#pragma unroll
        for (int p = 0; p < 4; p++) {
            const int row = sr + 32 * p;
            const size_t gb = (size_t)(n0 + row) * EE + k0 + sc;
            const int o = row*64 + dsw;
            *reinterpret_cast<ushort8*>(&sBh[o]) = *reinterpret_cast<const ushort8*>(&Bh[gb]);
            *reinterpret_cast<ushort8*>(&sBl[o]) = *reinterpret_cast<const ushort8*>(&Bl[gb]);
        }
        __syncthreads();
        const int mw = (wave >> 1) * 32;
        const int nw = (wave & 1) * 64;
#pragma unroll
        for (int ks = 0; ks < 2; ks++) {
            const int kc = ks*4 + l16;
            bf16x8 fah[2], fal[2], fbh[4], fbl[4];
#pragma unroll
            for (int i = 0; i < 2; i++) {
                const int ar = mw + 16*i + l15;
                const int ra = ar*64 + ((kc ^ (ar & 7)) << 3);
                fah[i] = *reinterpret_cast<const bf16x8*>(&sAh[ra]);
                fal[i] = *reinterpret_cast<const bf16x8*>(&sAl[ra]);
            }
#pragma unroll
            for (int j = 0; j < 4; j++) {
                const int br = nw + 16*j + l15;
                const int rb = br*64 + ((kc ^ (br & 7)) << 3);
                fbh[j] = *reinterpret_cast<const bf16x8*>(&sBh[rb]);
                fbl[j] = *reinterpret_cast<const bf16x8*>(&sBl[rb]);
            }
#pragma unroll
            for (int i = 0; i < 2; i++)
#pragma unroll
                for (int j = 0; j < 4; j++) {
                    acc[i][j] = __builtin_amdgcn_mfma_f32_16x16x32_bf16(fah[i], fbh[j], acc[i][j], 0, 0, 0);
                    acc[i][j] = __builtin_amdgcn_mfma_f32_16x16x32_bf16(fah[i], fbl[j], acc[i][j], 0, 0, 0);
                    acc[i][j] = __builtin_amdgcn_mfma_f32_16x16x32_bf16(fal[i], fbh[j], acc[i][j], 0, 0, 0);
                }
        }
        __syncthreads();
    }

    const int mw = (wave >> 1) * 32;
    const int nw = (wave & 1) * 64;
#pragma unroll
    for (int j = 0; j < 4; j++) {
        const int col = n0 + nw + 16*j + l15;            // 0..1535
        const int seg = col >> 9;                        // 0=Q 1=K 2=V
        const int c   = col & 511;
        const float bias = (seg == 0 ? bq : (seg == 1 ? bk : bv))[c];
        const float scale = (seg == 0) ? qscale : 1.0f;
        const int h = c >> 6, d = c & 63;
#pragma unroll
        for (int i = 0; i < 2; i++) {
            const int rowb = m0 + mw + 16*i + (l16 << 2);
#pragma unroll
            for (int r4 = 0; r4 < 4; r4++) {
                const int m = rowb + r4;
                const float val = (acc[i][j][r4] + bias) * scale;
                const int bb = m >> 11, s = m & (SS-1);
                const size_t idx = (((size_t)(bb*NH + h)) * SS + s) * DD + d;
                const uint16_t hi = f2bf(val);
                if (seg == 0)      { qh[idx] = hi; ql[idx] = f2bf(val - bf2f(hi)); }
                else if (seg == 1) { kh[idx] = hi; kl[idx] = f2bf(val - bf2f(hi)); }
                else               { vh[idx] = hi; }
            }
        }
    }
}

// ---------------- out-projection, BM=64, swizzled LDS (3 blocks/CU) ----------------
__global__ __launch_bounds__(256, 3)
void gemm_out(const uint16_t* __restrict__ Ah, const uint16_t* __restrict__ Al,
              const uint16_t* __restrict__ Bh, const uint16_t* __restrict__ Bl,
              const float* __restrict__ bo, float* __restrict__ Of)
{
    __shared__ uint16_t sAh[64*64], sAl[64*64], sBh[128*64], sBl[128*64];
    const int t = threadIdx.x;
    const int lane = t & 63;
    const int wave = t >> 6;
    const int m0 = blockIdx.x * 64;
    const int n0 = blockIdx.y * 128;

    f32x4 zero = {0.f, 0.f, 0.f, 0.f};
    f32x4 acc[2][4];
#pragma unroll
    for (int i = 0; i < 2; i++)
#pragma unroll
        for (int j = 0; j < 4; j++) acc[i][j] = zero;

    const int sr = t >> 3;
    const int c8 = t & 7;
    const int sc = c8 * 8;
    const int dsw = ((c8 ^ (sr & 7)) << 3);
    const int l15 = lane & 15;
    const int l16 = lane >> 4;

    for (int k0 = 0; k0 < EE; k0 += 64) {
#pragma unroll
        for (int p = 0; p < 2; p++) {
            const int row = sr + 32 * p;
            const size_t ga = (size_t)(m0 + row) * EE + k0 + sc;
            const int o = row*64 + dsw;
            *reinterpret_cast<ushort8*>(&sAh[o]) = *reinterpret_cast<const ushort8*>(&Ah[ga]);
            *reinterpret_cast<ushort8*>(&sAl[o]) = *reinterpret_cast<const ushort8*>(&Al[ga]);
        }
#pragma unroll
        for (int p = 0; p < 4; p++) {
            const int row = sr + 32 * p;
            const size_t gb = (size_t)(n0 + row) * EE + k0 + sc;
            const int o = row*64 + dsw;
            *reinterpret_cast<ushort8*>(&sBh[o]) = *reinterpret_cast<const ushort8*>(&Bh[gb]);
            *reinterpret_cast<ushort8*>(&sBl[o]) = *reinterpret_cast<const ushort8*>(&Bl[gb]);
        }
        __syncthreads();
        const int mw = (wave >> 1) * 32;
        const int nw = (wave & 1) * 64;
#pragma unroll
        for (int ks = 0; ks < 2; ks++) {
            const int kc = ks*4 + l16;
            bf16x8 fah[2], fal[2], fbh[4], fbl[4];
#pragma unroll
            for (int i = 0; i < 2; i++) {
                const int ar = mw + 16*i + l15;
                const int ra = ar*64 + ((kc ^ (ar & 7)) << 3);
                fah[i] = *reinterpret_cast<const bf16x8*>(&sAh[ra]);
                fal[i] = *reinterpret_cast<const bf16x8*>(&sAl[ra]);
            }
#pragma unroll
            for (int j = 0; j < 4; j++) {
                const int br = nw + 16*j + l15;
                const int rb = br*64 + ((kc ^ (br & 7)) << 3);
                fbh[j] = *reinterpret_cast<const bf16x8*>(&sBh[rb]);
                fbl[j] = *reinterpret_cast<const bf16x8*>(&sBl[rb]);
            }
#pragma unroll
            for (int i = 0; i < 2; i++)
#pragma unroll
                for (int j = 0; j < 4; j++) {
                    acc[i][j] = __builtin_amdgcn_mfma_f32_16x16x32_bf16(fah[i], fbh[j], acc[i][j], 0, 0, 0);
                    acc[i][j] = __builtin_amdgcn_mfma_f32_16x16x32_bf16(fah[i], fbl[j], acc[i][j], 0, 0, 0);
                    acc[i][j] = __builtin_amdgcn_mfma_f32_16x16x32_bf16(fal[i], fbh[j], acc[i][j], 0, 0, 0);
                }
        }
        __syncthreads();
    }

    const int mw = (wave >> 1) * 32;
    const int nw = (wave & 1) * 64;
#pragma unroll
    for (int j = 0; j < 4; j++) {
        const int col = n0 + nw + 16*j + l15;
        const float bv = bo[col];
#pragma unroll
        for (int i = 0; i < 2; i++) {
            const int rowb = m0 + mw + 16*i + (l16 << 2);
#pragma unroll
            for (int r4 = 0; r4 < 4; r4++)
                Of[(size_t)(rowb + r4) * EE + col] = acc[i][j][r4] + bv;
        }
    }
}

// ---------------- fused flash attention (round-7 known-good version) ----------------
// Phase 1: single-pass bf16 QK^T -> row sums (error ~1e-4 relative, see r7 analysis).
// Phase 2: 3-pass split scores, weights write, PV. 4 barriers/tile, padded LDS.
__global__ __launch_bounds__(256, 2)
void attn_fused(const uint16_t* __restrict__ Qh, const uint16_t* __restrict__ Ql,
                const uint16_t* __restrict__ Kh, const uint16_t* __restrict__ Kl,
                const uint16_t* __restrict__ Vh,
                float* __restrict__ attn,
                uint16_t* __restrict__ Oh, uint16_t* __restrict__ Ol)
{
    __shared__ __align__(16) uint16_t smem[36864];   // 73728 B -> 2 blocks/CU
    uint16_t* bufA = smem;          // K tile: hi [128][72] @0, lo @+9216 | phase2 W overlay [128][136]
    uint16_t* bufB = smem + 18432;  // phase1 dbuf partner (hi only) | phase2 V^T [64][136]

    const int t = threadIdx.x, lane = t & 63, wave = t >> 6;
    const int qt = blockIdx.x, bh = blockIdx.y;
    const size_t hb = (size_t)bh * SS * DD;
    const uint16_t* kbh = Kh + hb;
    const uint16_t* kbl = Kl + hb;
    const uint16_t* vbs = Vh + hb;

    const int l15 = lane & 15;
    const int l16 = lane >> 4;
    const int sr = t >> 3;        // 0..31
    const int sc = (t & 7) * 8;   // 0..56

    // ---- K staging regs (global->reg->LDS) ----
    ushort8 krh[4], krl[4];
    auto kload_hi = [&](int kt) {
#pragma unroll
        for (int p = 0; p < 4; p++) {
            const size_t g = (size_t)(kt*128 + sr + 32*p) * DD + sc;
            krh[p] = *reinterpret_cast<const ushort8*>(&kbh[g]);
        }
    };
    auto kwrite_hi = [&](uint16_t* buf) {
#pragma unroll
        for (int p = 0; p < 4; p++) {
            const int o = (sr + 32*p)*LDP + sc;
            *reinterpret_cast<ushort8*>(&buf[o]) = krh[p];
        }
    };
    auto kload = [&](int kt) {
#pragma unroll
        for (int p = 0; p < 4; p++) {
            const size_t g = (size_t)(kt*128 + sr + 32*p) * DD + sc;
            krh[p] = *reinterpret_cast<const ushort8*>(&kbh[g]);
            krl[p] = *reinterpret_cast<const ushort8*>(&kbl[g]);
        }
    };
    auto kwrite = [&](uint16_t* buf) {
#pragma unroll
        for (int p = 0; p < 4; p++) {
            const int o = (sr + 32*p)*LDP + sc;
            *reinterpret_cast<ushort8*>(&buf[o]) = krh[p];
            *reinterpret_cast<ushort8*>(&buf[9216 + o]) = krl[p];
        }
    };

    // ---- Q fragments in registers (persistent) ----
    bf16x8 qfh[2][2], qfl[2][2];
#pragma unroll
    for (int i = 0; i < 2; i++)
#pragma unroll
        for (int ks = 0; ks < 2; ks++) {
            const size_t qa = hb + (size_t)(qt*128 + wave*32 + 16*i + l15) * DD + ks*32 + l16*8;
            qfh[i][ks] = *reinterpret_cast<const bf16x8*>(&Qh[qa]);
            qfl[i][ks] = *reinterpret_cast<const bf16x8*>(&Ql[qa]);
        }

    f32x4 zero = {0.f, 0.f, 0.f, 0.f};
    f32x4 lsum[2] = {zero, zero};

    // ================= phase 1: row sums of exp2(scores), single-pass bf16 =================
    kload_hi(0);
#pragma unroll 1
    for (int kt = 0; kt < 16; kt++) {
        uint16_t* buf = (kt & 1) ? bufB : bufA;
        kwrite_hi(buf);
        if (kt < 15) kload_hi(kt + 1);
        __syncthreads();

        f32x4 accs[2][8];
#pragma unroll
        for (int i = 0; i < 2; i++)
#pragma unroll
            for (int j = 0; j < 8; j++) accs[i][j] = zero;

#pragma unroll
        for (int ks = 0; ks < 2; ks++) {
            const int kk = ks*32 + l16*8;
#pragma unroll
            for (int j = 0; j < 8; j++) {
                const int rb = (16*j + l15) * LDP + kk;
                bf16x8 fbh = *reinterpret_cast<const bf16x8*>(&buf[rb]);
#pragma unroll
                for (int i = 0; i < 2; i++)
                    accs[i][j] = __builtin_amdgcn_mfma_f32_16x16x32_bf16(qfh[i][ks], fbh, accs[i][j], 0, 0, 0);
            }
        }

#pragma unroll
        for (int i = 0; i < 2; i++)
#pragma unroll
            for (int j = 0; j < 8; j++)
#pragma unroll
                for (int r = 0; r < 4; r++)
                    lsum[i][r] += __builtin_amdgcn_exp2f(accs[i][j][r]);
    }

    // finalize: reduce over the 16-lane row group, invert
    f32x4 iv[2];
#pragma unroll
    for (int i = 0; i < 2; i++)
#pragma unroll
        for (int r = 0; r < 4; r++) {
            float s = lsum[i][r];
#pragma unroll
            for (int o = 1; o < 16; o <<= 1) s += __shfl_xor(s, o);
            iv[i][r] = 1.0f / s;
        }

    f32x4 acco[2][4];
#pragma unroll
    for (int i = 0; i < 2; i++)
#pragma unroll
        for (int j = 0; j < 4; j++) acco[i][j] = zero;

    float* wbase = attn + ((size_t)bh * SS + qt*128) * SS;

    // ---- V staging: pair-packed b32 writes (conflict-free) ----
    const int pk = t & 63;             // k-pair index (k = 2pk, 2pk+1)
    const int dbase = (t >> 6) * 16;   // d-quarter
    ushort8 vr[2][2];
    auto vload = [&](int kt) {
#pragma unroll
        for (int u = 0; u < 2; u++)
#pragma unroll
            for (int s = 0; s < 2; s++)
                vr[u][s] = *reinterpret_cast<const ushort8*>(
                    &vbs[(size_t)(kt*128 + 2*pk + s) * DD + dbase + u*8]);
    };
    auto vwrite = [&](uint16_t* vbufp) {
#pragma unroll
        for (int u = 0; u < 2; u++)
#pragma unroll
            for (int e = 0; e < 8; e++) {
                const int d = dbase + u*8 + e;
                const uint32_t pack = (uint32_t)(unsigned short)vr[u][0][e]
                                    | ((uint32_t)(unsigned short)vr[u][1][e] << 16);
                *reinterpret_cast<uint32_t*>(&vbufp[d*LDW + 2*pk]) = pack;
            }
    };

    __syncthreads();   // phase boundary: all phase-1 reads of bufB done

    // ================= phase 2: recompute (3-pass), write weights, PV =================
    kload(0); vload(0);
#pragma unroll 1
    for (int kt = 0; kt < 16; kt++) {
        kwrite(bufA);
        vwrite(bufB);
        __syncthreads();                       // bar1: K/V staged

        f32x4 accs[2][8];
#pragma unroll
        for (int i = 0; i < 2; i++)
#pragma unroll
            for (int j = 0; j < 8; j++) accs[i][j] = zero;
#pragma unroll
        for (int ks = 0; ks < 2; ks++) {
            const int kk = ks*32 + l16*8;
#pragma unroll
            for (int j = 0; j < 8; j++) {
                const int rb = (16*j + l15) * LDP + kk;
                bf16x8 fbh = *reinterpret_cast<const bf16x8*>(&bufA[rb]);
                bf16x8 fbl = *reinterpret_cast<const bf16x8*>(&bufA[9216 + rb]);
#pragma unroll
                for (int i = 0; i < 2; i++) {
                    accs[i][j] = __builtin_amdgcn_mfma_f32_16x16x32_bf16(qfh[i][ks], fbh, accs[i][j], 0, 0, 0);
                    accs[i][j] = __builtin_amdgcn_mfma_f32_16x16x32_bf16(qfh[i][ks], fbl, accs[i][j], 0, 0, 0);
                    accs[i][j] = __builtin_amdgcn_mfma_f32_16x16x32_bf16(qfl[i][ks], fbh, accs[i][j], 0, 0, 0);
                }
            }
        }

        // prefetch next tile's K/V while VALU works (T14)
        if (kt < 15) { kload(kt + 1); vload(kt + 1); }

        // normalize: w = exp2(s) * inv_sum (no max shift)
#pragma unroll
        for (int i = 0; i < 2; i++)
#pragma unroll
            for (int j = 0; j < 8; j++)
#pragma unroll
                for (int r = 0; r < 4; r++)
                    accs[i][j][r] = __builtin_amdgcn_exp2f(accs[i][j][r]) * iv[i][r];

        __syncthreads();                       // bar2: all K reads done

        // W bf16 -> bufA overlay
#pragma unroll
        for (int i = 0; i < 2; i++)
#pragma unroll
            for (int r = 0; r < 4; r++) {
                const int row = wave*32 + 16*i + l16*4 + r;
#pragma unroll
                for (int j = 0; j < 8; j++)
                    bufA[row*LDW + l15 + 16*j] = f2bf(accs[i][j][r]);
            }
        __syncthreads();                       // bar3: W/V visible

        // weight stores issued HERE: PV MFMA below hides the store latency,
        // bar4's vmcnt drain is then mostly pre-satisfied.
#pragma unroll
        for (int i = 0; i < 2; i++)
#pragma unroll
            for (int r = 0; r < 4; r++) {
                const int row = wave*32 + 16*i + l16*4 + r;
                float* wout = wbase + (size_t)row * SS + kt*128 + l15;
#pragma unroll
                for (int j = 0; j < 8; j++) wout[16*j] = accs[i][j][r];
            }

        // PV: O += W @ V
#pragma unroll
        for (int ks = 0; ks < 4; ks++) {
            const int kk = ks*32 + l16*8;
            bf16x8 wa[2], vbf[4];
#pragma unroll
            for (int i = 0; i < 2; i++)
                wa[i] = *reinterpret_cast<const bf16x8*>(&bufA[(wave*32 + 16*i + l15)*LDW + kk]);
#pragma unroll
            for (int j = 0; j < 4; j++)
                vbf[j] = *reinterpret_cast<const bf16x8*>(&bufB[(16*j + l15)*LDW + kk]);
#pragma unroll
            for (int i = 0; i < 2; i++)
#pragma unroll
                for (int j = 0; j < 4; j++)
                    acco[i][j] = __builtin_amdgcn_mfma_f32_16x16x32_bf16(wa[i], vbf[j], acco[i][j], 0, 0, 0);
        }
        __syncthreads();                       // bar4: PV reads + stores drained
    }

    // epilogue: attn_output split-bf16 into [b, s, h*64+d]
    const int b = bh >> 3, h = bh & 7;
#pragma unroll
    for (int i = 0; i < 2; i++)
#pragma unroll
        for (int j = 0; j < 4; j++)
#pragma unroll
            for (int r4 = 0; r4 < 4; r4++) {
                const int srow = qt*128 + wave*32 + 16*i + (l16 << 2) + r4;
                const int col = h*64 + 16*j + l15;
                const size_t idx = ((size_t)b * SS + srow) * (size_t)EE + col;
                const float val = acco[i][j][r4];
                const uint16_t hh = f2bf(val);
                Oh[idx] = hh;
                Ol[idx] = f2bf(val - bf2f(hh));
            }
}

extern "C" void kernel_launch(void* const* d_in, const int* in_sizes, int n_in,
                              void* d_out, int out_size, void* d_ws, size_t ws_size,
                              hipStream_t stream)
{
    const float* x  = (const float*)d_in[0];
    const float* Wq = (const float*)d_in[1];
    const float* bq = (const float*)d_in[2];
    const float* Wk = (const float*)d_in[3];
    const float* bk = (const float*)d_in[4];
    const float* Wv = (const float*)d_in[5];
    const float* bv = (const float*)d_in[6];
    const float* Wo = (const float*)d_in[7];
    const float* bo = (const float*)d_in[8];

    float* outF = (float*)d_out;
    float* attn = outF + (size_t)MM * EE;   // output 1 region (normalized weights)

    const size_t NXE = (size_t)MM * EE;     // 4,194,304
    const size_t NW  = (size_t)EE * EE;     // 262,144
    uint16_t* p = (uint16_t*)d_ws;
    uint16_t* xh    = p;          p += NXE;
    uint16_t* xl    = p;          p += NXE;
    uint16_t* wqkvh = p;          p += 3*NW;
    uint16_t* wqkvl = p;          p += 3*NW;
    uint16_t* woh   = p;          p += NW;
    uint16_t* wol   = p;          p += NW;
    uint16_t* qh    = p;          p += NXE;
    uint16_t* ql    = p;          p += NXE;
    uint16_t* kh    = p;          p += NXE;
    uint16_t* kl    = p;          p += NXE;
    uint16_t* vh    = p;          p += NXE;
    uint16_t* ah    = p;          p += NXE;
    uint16_t* al    = p;          p += NXE;

    split_all<<<4096 + 4*256, 256, 0, stream>>>(x, Wq, Wk, Wv, Wo,
                                                xh, xl, wqkvh, wqkvl, woh, wol);

    // Q scaled by 0.125*log2(e): scores land in log2 units -> softmax uses exp2 directly
    const float qscale = 0.125f * 1.44269504088896340736f;
    gemm_qkv<<<dim3(MM/64, (3*EE)/128), 256, 0, stream>>>(
        xh, xl, wqkvh, wqkvl, bq, bk, bv, qscale, qh, ql, kh, kl, vh);

    attn_fused<<<dim3(SS/128, NB*NH), 256, 0, stream>>>(qh, ql, kh, kl, vh, attn, ah, al);

    gemm_out<<<dim3(MM/64, EE/128), 256, 0, stream>>>(ah, al, woh, wol, bo, outF);
}

// Round 13
// 249.907 us; speedup vs baseline: 1.9854x; 1.0001x over previous
//
#include <hip/hip_runtime.h>
#include <stdint.h>

#define NB 4
#define NH 8
#define SS 2048
#define EE 512
#define DD 64
#define MM (NB*SS)      // 8192
#define LDP 72          // padded LDS row (bf16 elems) for K-dim-64 tiles (attn)
#define LDW 136         // padded LDS row for 128-wide W / V^T tiles (attn)

typedef __attribute__((ext_vector_type(8))) __bf16 bf16x8;
typedef __attribute__((ext_vector_type(8))) unsigned short ushort8;
typedef __attribute__((ext_vector_type(4))) unsigned short ushort4v;
typedef __attribute__((ext_vector_type(4))) float f32x4;

__device__ __forceinline__ uint16_t f2bf(float f) {
    union { float f; uint32_t u; } v; v.f = f;
    return (uint16_t)((v.u + 0x7fffu + ((v.u >> 16) & 1u)) >> 16);   // RNE
}
__device__ __forceinline__ float bf2f(uint16_t h) {
    union { uint32_t u; float f; } v; v.u = ((uint32_t)h) << 16;
    return v.f;
}

// ---------------- merged split: x + Wq/Wk/Wv/Wo -> bf16 hi/lo ----------------
__global__ __launch_bounds__(256) void split_all(
        const float* __restrict__ x,  const float* __restrict__ Wq,
        const float* __restrict__ Wk, const float* __restrict__ Wv,
        const float* __restrict__ Wo,
        uint16_t* __restrict__ xh, uint16_t* __restrict__ xl,
        uint16_t* __restrict__ wqkvh, uint16_t* __restrict__ wqkvl,
        uint16_t* __restrict__ woh, uint16_t* __restrict__ wol)
{
    const int tid = threadIdx.x;
    int b = blockIdx.x;
    const float* src; uint16_t* dh; uint16_t* dl; int i;
    if (b < 4096) { src = x; dh = xh; dl = xl; i = b*256 + tid; }
    else {
        b -= 4096;
        const int seg = b >> 8;                 // 0..3
        i = (b & 255)*256 + tid;
        src = (seg == 0) ? Wq : (seg == 1) ? Wk : (seg == 2) ? Wv : Wo;
        if (seg < 3) { dh = wqkvh + (size_t)seg*262144; dl = wqkvl + (size_t)seg*262144; }
        else         { dh = woh; dl = wol; }
    }
    f32x4 v = reinterpret_cast<const f32x4*>(src)[i];
    ushort4v h, l;
#pragma unroll
    for (int j = 0; j < 4; j++) {
        uint16_t hh = f2bf(v[j]);
        h[j] = hh;
        l[j] = f2bf(v[j] - bf2f(hh));
    }
    reinterpret_cast<ushort4v*>(dh)[i] = h;
    reinterpret_cast<ushort4v*>(dl)[i] = l;
}

// ---------------- merged QKV projection, BM=64, swizzled LDS (3 blocks/CU) ----------------
__global__ __launch_bounds__(256, 3)
void gemm_qkv(const uint16_t* __restrict__ Ah, const uint16_t* __restrict__ Al,
              const uint16_t* __restrict__ Bh, const uint16_t* __restrict__ Bl,
              const float* __restrict__ bq, const float* __restrict__ bk,
              const float* __restrict__ bv, float qscale,
              uint16_t* __restrict__ qh, uint16_t* __restrict__ ql,
              uint16_t* __restrict__ kh, uint16_t* __restrict__ kl,
              uint16_t* __restrict__ vh)
{
    __shared__ uint16_t sAh[64*64], sAl[64*64], sBh[128*64], sBl[128*64];
    const int t = threadIdx.x;
    const int lane = t & 63;
    const int wave = t >> 6;
    const int m0 = blockIdx.x * 64;
    const int n0 = blockIdx.y * 128;

    f32x4 zero = {0.f, 0.f, 0.f, 0.f};
    f32x4 acc[2][4];
#pragma unroll
    for (int i = 0; i < 2; i++)
#pragma unroll
        for (int j = 0; j < 4; j++) acc[i][j] = zero;

    const int sr = t >> 3;        // 0..31
    const int c8 = t & 7;         // source chunk
    const int sc = c8 * 8;
    const int dsw = ((c8 ^ (sr & 7)) << 3);   // swizzled dest chunk offset
    const int l15 = lane & 15;
    const int l16 = lane >> 4;

    for (int k0 = 0; k0 < EE; k0 += 64) {
#pragma unroll
        for (int p = 0; p < 2; p++) {
            const int row = sr + 32 * p;
            const size_t ga = (size_t)(m0 + row) * EE + k0 + sc;
            const int o = row*64 + dsw;
            *reinterpret_cast<ushort8*>(&sAh[o]) = *reinterpret_cast<const ushort8*>(&Ah[ga]);
            *reinterpret_cast<ushort8*>(&sAl[o]) = *reinterpret_cast<const ushort8*>(&Al[ga]);
        }
#pragma unroll
        for (int p = 0; p < 4; p++) {
            const int row = sr + 32 * p;
            const size_t gb = (size_t)(n0 + row) * EE + k0 + sc;
            const int o = row*64 + dsw;
            *reinterpret_cast<ushort8*>(&sBh[o]) = *reinterpret_cast<const ushort8*>(&Bh[gb]);
            *reinterpret_cast<ushort8*>(&sBl[o]) = *reinterpret_cast<const ushort8*>(&Bl[gb]);
        }
        __syncthreads();
        const int mw = (wave >> 1) * 32;
        const int nw = (wave & 1) * 64;
#pragma unroll
        for (int ks = 0; ks < 2; ks++) {
            const int kc = ks*4 + l16;
            bf16x8 fah[2], fal[2], fbh[4], fbl[4];
#pragma unroll
            for (int i = 0; i < 2; i++) {
                const int ar = mw + 16*i + l15;
                const int ra = ar*64 + ((kc ^ (ar & 7)) << 3);
                fah[i] = *reinterpret_cast<const bf16x8*>(&sAh[ra]);
                fal[i] = *reinterpret_cast<const bf16x8*>(&sAl[ra]);
            }
#pragma unroll
            for (int j = 0; j < 4; j++) {
                const int br = nw + 16*j + l15;
                const int rb = br*64 + ((kc ^ (br & 7)) << 3);
                fbh[j] = *reinterpret_cast<const bf16x8*>(&sBh[rb]);
                fbl[j] = *reinterpret_cast<const bf16x8*>(&sBl[rb]);
            }
#pragma unroll
            for (int i = 0; i < 2; i++)
#pragma unroll
                for (int j = 0; j < 4; j++) {
                    acc[i][j] = __builtin_amdgcn_mfma_f32_16x16x32_bf16(fah[i], fbh[j], acc[i][j], 0, 0, 0);
                    acc[i][j] = __builtin_amdgcn_mfma_f32_16x16x32_bf16(fah[i], fbl[j], acc[i][j], 0, 0, 0);
                    acc[i][j] = __builtin_amdgcn_mfma_f32_16x16x32_bf16(fal[i], fbh[j], acc[i][j], 0, 0, 0);
                }
        }
        __syncthreads();
    }

    const int mw = (wave >> 1) * 32;
    const int nw = (wave & 1) * 64;
#pragma unroll
    for (int j = 0; j < 4; j++) {
        const int col = n0 + nw + 16*j + l15;            // 0..1535
        const int seg = col >> 9;                        // 0=Q 1=K 2=V
        const int c   = col & 511;
        const float bias = (seg == 0 ? bq : (seg == 1 ? bk : bv))[c];
        const float scale = (seg == 0) ? qscale : 1.0f;
        const int h = c >> 6, d = c & 63;
#pragma unroll
        for (int i = 0; i < 2; i++) {
            const int rowb = m0 + mw + 16*i + (l16 << 2);
#pragma unroll
            for (int r4 = 0; r4 < 4; r4++) {
                const int m = rowb + r4;
                const float val = (acc[i][j][r4] + bias) * scale;
                const int bb = m >> 11, s = m & (SS-1);
                const size_t idx = (((size_t)(bb*NH + h)) * SS + s) * DD + d;
                const uint16_t hi = f2bf(val);
                if (seg == 0)      { qh[idx] = hi; ql[idx] = f2bf(val - bf2f(hi)); }
                else if (seg == 1) { kh[idx] = hi; kl[idx] = f2bf(val - bf2f(hi)); }
                else               { vh[idx] = hi; }
            }
        }
    }
}

// ---------------- out-projection, BM=64, swizzled LDS (3 blocks/CU) ----------------
__global__ __launch_bounds__(256, 3)
void gemm_out(const uint16_t* __restrict__ Ah, const uint16_t* __restrict__ Al,
              const uint16_t* __restrict__ Bh, const uint16_t* __restrict__ Bl,
              const float* __restrict__ bo, float* __restrict__ Of)
{
    __shared__ uint16_t sAh[64*64], sAl[64*64], sBh[128*64], sBl[128*64];
    const int t = threadIdx.x;
    const int lane = t & 63;
    const int wave = t >> 6;
    const int m0 = blockIdx.x * 64;
    const int n0 = blockIdx.y * 128;

    f32x4 zero = {0.f, 0.f, 0.f, 0.f};
    f32x4 acc[2][4];
#pragma unroll
    for (int i = 0; i < 2; i++)
#pragma unroll
        for (int j = 0; j < 4; j++) acc[i][j] = zero;

    const int sr = t >> 3;
    const int c8 = t & 7;
    const int sc = c8 * 8;
    const int dsw = ((c8 ^ (sr & 7)) << 3);
    const int l15 = lane & 15;
    const int l16 = lane >> 4;

    for (int k0 = 0; k0 < EE; k0 += 64) {
#pragma unroll
        for (int p = 0; p < 2; p++) {
            const int row = sr + 32 * p;
            const size_t ga = (size_t)(m0 + row) * EE + k0 + sc;
            const int o = row*64 + dsw;
            *reinterpret_cast<ushort8*>(&sAh[o]) = *reinterpret_cast<const ushort8*>(&Ah[ga]);
            *reinterpret_cast<ushort8*>(&sAl[o]) = *reinterpret_cast<const ushort8*>(&Al[ga]);
        }
#pragma unroll
        for (int p = 0; p < 4; p++) {
            const int row = sr + 32 * p;
            const size_t gb = (size_t)(n0 + row) * EE + k0 + sc;
            const int o = row*64 + dsw;
            *reinterpret_cast<ushort8*>(&sBh[o]) = *reinterpret_cast<const ushort8*>(&Bh[gb]);
            *reinterpret_cast<ushort8*>(&sBl[o]) = *reinterpret_cast<const ushort8*>(&Bl[gb]);
        }
        __syncthreads();
        const int mw = (wave >> 1) * 32;
        const int nw = (wave & 1) * 64;
#pragma unroll
        for (int ks = 0; ks < 2; ks++) {
            const int kc = ks*4 + l16;
            bf16x8 fah[2], fal[2], fbh[4], fbl[4];
#pragma unroll
            for (int i = 0; i < 2; i++) {
                const int ar = mw + 16*i + l15;
                const int ra = ar*64 + ((kc ^ (ar & 7)) << 3);
                fah[i] = *reinterpret_cast<const bf16x8*>(&sAh[ra]);
                fal[i] = *reinterpret_cast<const bf16x8*>(&sAl[ra]);
            }
#pragma unroll
            for (int j = 0; j < 4; j++) {
                const int br = nw + 16*j + l15;
                const int rb = br*64 + ((kc ^ (br & 7)) << 3);
                fbh[j] = *reinterpret_cast<const bf16x8*>(&sBh[rb]);
                fbl[j] = *reinterpret_cast<const bf16x8*>(&sBl[rb]);
            }
#pragma unroll
            for (int i = 0; i < 2; i++)
#pragma unroll
                for (int j = 0; j < 4; j++) {
                    acc[i][j] = __builtin_amdgcn_mfma_f32_16x16x32_bf16(fah[i], fbh[j], acc[i][j], 0, 0, 0);
                    acc[i][j] = __builtin_amdgcn_mfma_f32_16x16x32_bf16(fah[i], fbl[j], acc[i][j], 0, 0, 0);
                    acc[i][j] = __builtin_amdgcn_mfma_f32_16x16x32_bf16(fal[i], fbh[j], acc[i][j], 0, 0, 0);
                }
        }
        __syncthreads();
    }

    const int mw = (wave >> 1) * 32;
    const int nw = (wave & 1) * 64;
#pragma unroll
    for (int j = 0; j < 4; j++) {
        const int col = n0 + nw + 16*j + l15;
        const float bv = bo[col];
#pragma unroll
        for (int i = 0; i < 2; i++) {
            const int rowb = m0 + mw + 16*i + (l16 << 2);
#pragma unroll
            for (int r4 = 0; r4 < 4; r4++)
                Of[(size_t)(rowb + r4) * EE + col] = acc[i][j][r4] + bv;
        }
    }
}

// ---------------- fused flash attention (round-7/11 known-good version) ----------------
// Phase 1: single-pass bf16 QK^T -> row sums (error ~1e-4 relative).
// Phase 2: 3-pass split scores, weights write, PV. 4 barriers/tile, padded LDS.
__global__ __launch_bounds__(256, 2)
void attn_fused(const uint16_t* __restrict__ Qh, const uint16_t* __restrict__ Ql,
                const uint16_t* __restrict__ Kh, const uint16_t* __restrict__ Kl,
                const uint16_t* __restrict__ Vh,
                float* __restrict__ attn,
                uint16_t* __restrict__ Oh, uint16_t* __restrict__ Ol)
{
    __shared__ __align__(16) uint16_t smem[36864];   // 73728 B -> 2 blocks/CU
    uint16_t* bufA = smem;          // K tile: hi [128][72] @0, lo @+9216 | phase2 W overlay [128][136]
    uint16_t* bufB = smem + 18432;  // phase1 dbuf partner (hi only) | phase2 V^T [64][136]

    const int t = threadIdx.x, lane = t & 63, wave = t >> 6;
    const int qt = blockIdx.x, bh = blockIdx.y;
    const size_t hb = (size_t)bh * SS * DD;
    const uint16_t* kbh = Kh + hb;
    const uint16_t* kbl = Kl + hb;
    const uint16_t* vbs = Vh + hb;

    const int l15 = lane & 15;
    const int l16 = lane >> 4;
    const int sr = t >> 3;        // 0..31
    const int sc = (t & 7) * 8;   // 0..56

    // ---- K staging regs (global->reg->LDS) ----
    ushort8 krh[4], krl[4];
    auto kload_hi = [&](int kt) {
#pragma unroll
        for (int p = 0; p < 4; p++) {
            const size_t g = (size_t)(kt*128 + sr + 32*p) * DD + sc;
            krh[p] = *reinterpret_cast<const ushort8*>(&kbh[g]);
        }
    };
    auto kwrite_hi = [&](uint16_t* buf) {
#pragma unroll
        for (int p = 0; p < 4; p++) {
            const int o = (sr + 32*p)*LDP + sc;
            *reinterpret_cast<ushort8*>(&buf[o]) = krh[p];
        }
    };
    auto kload = [&](int kt) {
#pragma unroll
        for (int p = 0; p < 4; p++) {
            const size_t g = (size_t)(kt*128 + sr + 32*p) * DD + sc;
            krh[p] = *reinterpret_cast<const ushort8*>(&kbh[g]);
            krl[p] = *reinterpret_cast<const ushort8*>(&kbl[g]);
        }
    };
    auto kwrite = [&](uint16_t* buf) {
#pragma unroll
        for (int p = 0; p < 4; p++) {
            const int o = (sr + 32*p)*LDP + sc;
            *reinterpret_cast<ushort8*>(&buf[o]) = krh[p];
            *reinterpret_cast<ushort8*>(&buf[9216 + o]) = krl[p];
        }
    };

    // ---- Q fragments in registers (persistent) ----
    bf16x8 qfh[2][2], qfl[2][2];
#pragma unroll
    for (int i = 0; i < 2; i++)
#pragma unroll
        for (int ks = 0; ks < 2; ks++) {
            const size_t qa = hb + (size_t)(qt*128 + wave*32 + 16*i + l15) * DD + ks*32 + l16*8;
            qfh[i][ks] = *reinterpret_cast<const bf16x8*>(&Qh[qa]);
            qfl[i][ks] = *reinterpret_cast<const bf16x8*>(&Ql[qa]);
        }

    f32x4 zero = {0.f, 0.f, 0.f, 0.f};
    f32x4 lsum[2] = {zero, zero};

    // ================= phase 1: row sums of exp2(scores), single-pass bf16 =================
    kload_hi(0);
#pragma unroll 1
    for (int kt = 0; kt < 16; kt++) {
        uint16_t* buf = (kt & 1) ? bufB : bufA;
        kwrite_hi(buf);
        if (kt < 15) kload_hi(kt + 1);
        __syncthreads();

        f32x4 accs[2][8];
#pragma unroll
        for (int i = 0; i < 2; i++)
#pragma unroll
            for (int j = 0; j < 8; j++) accs[i][j] = zero;

#pragma unroll
        for (int ks = 0; ks < 2; ks++) {
            const int kk = ks*32 + l16*8;
#pragma unroll
            for (int j = 0; j < 8; j++) {
                const int rb = (16*j + l15) * LDP + kk;
                bf16x8 fbh = *reinterpret_cast<const bf16x8*>(&buf[rb]);
#pragma unroll
                for (int i = 0; i < 2; i++)
                    accs[i][j] = __builtin_amdgcn_mfma_f32_16x16x32_bf16(qfh[i][ks], fbh, accs[i][j], 0, 0, 0);
            }
        }

#pragma unroll
        for (int i = 0; i < 2; i++)
#pragma unroll
            for (int j = 0; j < 8; j++)
#pragma unroll
                for (int r = 0; r < 4; r++)
                    lsum[i][r] += __builtin_amdgcn_exp2f(accs[i][j][r]);
    }

    // finalize: reduce over the 16-lane row group, invert
    f32x4 iv[2];
#pragma unroll
    for (int i = 0; i < 2; i++)
#pragma unroll
        for (int r = 0; r < 4; r++) {
            float s = lsum[i][r];
#pragma unroll
            for (int o = 1; o < 16; o <<= 1) s += __shfl_xor(s, o);
            iv[i][r] = 1.0f / s;
        }

    f32x4 acco[2][4];
#pragma unroll
    for (int i = 0; i < 2; i++)
#pragma unroll
        for (int j = 0; j < 4; j++) acco[i][j] = zero;

    float* wbase = attn + ((size_t)bh * SS + qt*128) * SS;

    // ---- V staging: pair-packed b32 writes (conflict-free) ----
    const int pk = t & 63;             // k-pair index (k = 2pk, 2pk+1)
    const int dbase = (t >> 6) * 16;   // d-quarter
    ushort8 vr[2][2];
    auto vload = [&](int kt) {
#pragma unroll
        for (int u = 0; u < 2; u++)
#pragma unroll
            for (int s = 0; s < 2; s++)
                vr[u][s] = *reinterpret_cast<const ushort8*>(
                    &vbs[(size_t)(kt*128 + 2*pk + s) * DD + dbase + u*8]);
    };
    auto vwrite = [&](uint16_t* vbufp) {
#pragma unroll
        for (int u = 0; u < 2; u++)
#pragma unroll
            for (int e = 0; e < 8; e++) {
                const int d = dbase + u*8 + e;
                const uint32_t pack = (uint32_t)(unsigned short)vr[u][0][e]
                                    | ((uint32_t)(unsigned short)vr[u][1][e] << 16);
                *reinterpret_cast<uint32_t*>(&vbufp[d*LDW + 2*pk]) = pack;
            }
    };

    __syncthreads();   // phase boundary: all phase-1 reads of bufB done

    // ================= phase 2: recompute (3-pass), write weights, PV =================
    kload(0); vload(0);
#pragma unroll 1
    for (int kt = 0; kt < 16; kt++) {
        kwrite(bufA);
        vwrite(bufB);
        __syncthreads();                       // bar1: K/V staged

        f32x4 accs[2][8];
#pragma unroll
        for (int i = 0; i < 2; i++)
#pragma unroll
            for (int j = 0; j < 8; j++) accs[i][j] = zero;
#pragma unroll
        for (int ks = 0; ks < 2; ks++) {
            const int kk = ks*32 + l16*8;
#pragma unroll
            for (int j = 0; j < 8; j++) {
                const int rb = (16*j + l15) * LDP + kk;
                bf16x8 fbh = *reinterpret_cast<const bf16x8*>(&bufA[rb]);
                bf16x8 fbl = *reinterpret_cast<const bf16x8*>(&bufA[9216 + rb]);
#pragma unroll
                for (int i = 0; i < 2; i++) {
                    accs[i][j] = __builtin_amdgcn_mfma_f32_16x16x32_bf16(qfh[i][ks], fbh, accs[i][j], 0, 0, 0);
                    accs[i][j] = __builtin_amdgcn_mfma_f32_16x16x32_bf16(qfh[i][ks], fbl, accs[i][j], 0, 0, 0);
                    accs[i][j] = __builtin_amdgcn_mfma_f32_16x16x32_bf16(qfl[i][ks], fbh, accs[i][j], 0, 0, 0);
                }
            }
        }

        // prefetch next tile's K/V while VALU works (T14)
        if (kt < 15) { kload(kt + 1); vload(kt + 1); }

        // normalize: w = exp2(s) * inv_sum (no max shift)
#pragma unroll
        for (int i = 0; i < 2; i++)
#pragma unroll
            for (int j = 0; j < 8; j++)
#pragma unroll
                for (int r = 0; r < 4; r++)
                    accs[i][j][r] = __builtin_amdgcn_exp2f(accs[i][j][r]) * iv[i][r];

        __syncthreads();                       // bar2: all K reads done

        // W bf16 -> bufA overlay
#pragma unroll
        for (int i = 0; i < 2; i++)
#pragma unroll
            for (int r = 0; r < 4; r++) {
                const int row = wave*32 + 16*i + l16*4 + r;
#pragma unroll
                for (int j = 0; j < 8; j++)
                    bufA[row*LDW + l15 + 16*j] = f2bf(accs[i][j][r]);
            }
        __syncthreads();                       // bar3: W/V visible

        // weight stores issued HERE: PV MFMA below hides the store latency,
        // bar4's vmcnt drain is then mostly pre-satisfied.
#pragma unroll
        for (int i = 0; i < 2; i++)
#pragma unroll
            for (int r = 0; r < 4; r++) {
                const int row = wave*32 + 16*i + l16*4 + r;
                float* wout = wbase + (size_t)row * SS + kt*128 + l15;
#pragma unroll
                for (int j = 0; j < 8; j++) wout[16*j] = accs[i][j][r];
            }

        // PV: O += W @ V
#pragma unroll
        for (int ks = 0; ks < 4; ks++) {
            const int kk = ks*32 + l16*8;
            bf16x8 wa[2], vbf[4];
#pragma unroll
            for (int i = 0; i < 2; i++)
                wa[i] = *reinterpret_cast<const bf16x8*>(&bufA[(wave*32 + 16*i + l15)*LDW + kk]);
#pragma unroll
            for (int j = 0; j < 4; j++)
                vbf[j] = *reinterpret_cast<const bf16x8*>(&bufB[(16*j + l15)*LDW + kk]);
#pragma unroll
            for (int i = 0; i < 2; i++)
#pragma unroll
                for (int j = 0; j < 4; j++)
                    acco[i][j] = __builtin_amdgcn_mfma_f32_16x16x32_bf16(wa[i], vbf[j], acco[i][j], 0, 0, 0);
        }
        __syncthreads();                       // bar4: PV reads + stores drained
    }

    // epilogue: attn_output split-bf16 into [b, s, h*64+d]
    const int b = bh >> 3, h = bh & 7;
#pragma unroll
    for (int i = 0; i < 2; i++)
#pragma unroll
        for (int j = 0; j < 4; j++)
#pragma unroll
            for (int r4 = 0; r4 < 4; r4++) {
                const int srow = qt*128 + wave*32 + 16*i + (l16 << 2) + r4;
                const int col = h*64 + 16*j + l15;
                const size_t idx = ((size_t)b * SS + srow) * (size_t)EE + col;
                const float val = acco[i][j][r4];
                const uint16_t hh = f2bf(val);
                Oh[idx] = hh;
                Ol[idx] = f2bf(val - bf2f(hh));
            }
}

extern "C" void kernel_launch(void* const* d_in, const int* in_sizes, int n_in,
                              void* d_out, int out_size, void* d_ws, size_t ws_size,
                              hipStream_t stream)
{
    const float* x  = (const float*)d_in[0];
    const float* Wq = (const float*)d_in[1];
    const float* bq = (const float*)d_in[2];
    const float* Wk = (const float*)d_in[3];
    const float* bk = (const float*)d_in[4];
    const float* Wv = (const float*)d_in[5];
    const float* bv = (const float*)d_in[6];
    const float* Wo = (const float*)d_in[7];
    const float* bo = (const float*)d_in[8];

    float* outF = (float*)d_out;
    float* attn = outF + (size_t)MM * EE;   // output 1 region (normalized weights)

    const size_t NXE = (size_t)MM * EE;     // 4,194,304
    const size_t NW  = (size_t)EE * EE;     // 262,144
    uint16_t* p = (uint16_t*)d_ws;
    uint16_t* xh    = p;          p += NXE;
    uint16_t* xl    = p;          p += NXE;
    uint16_t* wqkvh = p;          p += 3*NW;
    uint16_t* wqkvl = p;          p += 3*NW;
    uint16_t* woh   = p;          p += NW;
    uint16_t* wol   = p;          p += NW;
    uint16_t* qh    = p;          p += NXE;
    uint16_t* ql    = p;          p += NXE;
    uint16_t* kh    = p;          p += NXE;
    uint16_t* kl    = p;          p += NXE;
    uint16_t* vh    = p;          p += NXE;
    uint16_t* ah    = p;          p += NXE;
    uint16_t* al    = p;          p += NXE;

    split_all<<<4096 + 4*256, 256, 0, stream>>>(x, Wq, Wk, Wv, Wo,
                                                xh, xl, wqkvh, wqkvl, woh, wol);

    // Q scaled by 0.125*log2(e): scores land in log2 units -> softmax uses exp2 directly
    const float qscale = 0.125f * 1.44269504088896340736f;
    gemm_qkv<<<dim3(MM/64, (3*EE)/128), 256, 0, stream>>>(
        xh, xl, wqkvh, wqkvl, bq, bk, bv, qscale, qh, ql, kh, kl, vh);

    attn_fused<<<dim3(SS/128, NB*NH), 256, 0, stream>>>(qh, ql, kh, kl, vh, attn, ah, al);

    gemm_out<<<dim3(MM/64, EE/128), 256, 0, stream>>>(ah, al, woh, wol, bo, outF);
}

// Round 14
// 244.703 us; speedup vs baseline: 2.0276x; 1.0213x over previous
//
#include <hip/hip_runtime.h>
#include <stdint.h>

#define NB 4
#define NH 8
#define SS 2048
#define EE 512
#define DD 64
#define MM (NB*SS)      // 8192
#define LDP 72          // padded LDS row (bf16 elems) for K-dim-64 tiles (attn)
#define LDW 136         // padded LDS row for 128-wide W / V^T tiles (attn)

typedef __attribute__((ext_vector_type(8))) __bf16 bf16x8;
typedef __attribute__((ext_vector_type(8))) unsigned short ushort8;
typedef __attribute__((ext_vector_type(4))) unsigned short ushort4v;
typedef __attribute__((ext_vector_type(4))) float f32x4;

__device__ __forceinline__ uint16_t f2bf(float f) {
    union { float f; uint32_t u; } v; v.f = f;
    return (uint16_t)((v.u + 0x7fffu + ((v.u >> 16) & 1u)) >> 16);   // RNE
}
__device__ __forceinline__ float bf2f(uint16_t h) {
    union { uint32_t u; float f; } v; v.u = ((uint32_t)h) << 16;
    return v.f;
}

// ---------------- merged split: x + Wq/Wk/Wv/Wo -> bf16 hi/lo ----------------
__global__ __launch_bounds__(256) void split_all(
        const float* __restrict__ x,  const float* __restrict__ Wq,
        const float* __restrict__ Wk, const float* __restrict__ Wv,
        const float* __restrict__ Wo,
        uint16_t* __restrict__ xh, uint16_t* __restrict__ xl,
        uint16_t* __restrict__ wqkvh, uint16_t* __restrict__ wqkvl,
        uint16_t* __restrict__ woh, uint16_t* __restrict__ wol)
{
    const int tid = threadIdx.x;
    int b = blockIdx.x;
    const float* src; uint16_t* dh; uint16_t* dl; int i;
    if (b < 4096) { src = x; dh = xh; dl = xl; i = b*256 + tid; }
    else {
        b -= 4096;
        const int seg = b >> 8;                 // 0..3
        i = (b & 255)*256 + tid;
        src = (seg == 0) ? Wq : (seg == 1) ? Wk : (seg == 2) ? Wv : Wo;
        if (seg < 3) { dh = wqkvh + (size_t)seg*262144; dl = wqkvl + (size_t)seg*262144; }
        else         { dh = woh; dl = wol; }
    }
    f32x4 v = reinterpret_cast<const f32x4*>(src)[i];
    ushort4v h, l;
#pragma unroll
    for (int j = 0; j < 4; j++) {
        uint16_t hh = f2bf(v[j]);
        h[j] = hh;
        l[j] = f2bf(v[j] - bf2f(hh));
    }
    reinterpret_cast<ushort4v*>(dh)[i] = h;
    reinterpret_cast<ushort4v*>(dl)[i] = l;
}

// ---------------- merged QKV projection, BM=64, swizzled LDS (3 blocks/CU) ----------------
__global__ __launch_bounds__(256, 3)
void gemm_qkv(const uint16_t* __restrict__ Ah, const uint16_t* __restrict__ Al,
              const uint16_t* __restrict__ Bh, const uint16_t* __restrict__ Bl,
              const float* __restrict__ bq, const float* __restrict__ bk,
              const float* __restrict__ bv, float qscale,
              uint16_t* __restrict__ qh, uint16_t* __restrict__ ql,
              uint16_t* __restrict__ kh, uint16_t* __restrict__ kl,
              uint16_t* __restrict__ vh)
{
    __shared__ uint16_t sAh[64*64], sAl[64*64], sBh[128*64], sBl[128*64];
    const int t = threadIdx.x;
    const int lane = t & 63;
    const int wave = t >> 6;
    const int m0 = blockIdx.x * 64;
    const int n0 = blockIdx.y * 128;

    f32x4 zero = {0.f, 0.f, 0.f, 0.f};
    f32x4 acc[2][4];
#pragma unroll
    for (int i = 0; i < 2; i++)
#pragma unroll
        for (int j = 0; j < 4; j++) acc[i][j] = zero;

    const int sr = t >> 3;        // 0..31
    const int c8 = t & 7;         // source chunk
    const int sc = c8 * 8;
    const int dsw = ((c8 ^ (sr & 7)) << 3);   // swizzled dest chunk offset
    const int l15 = lane & 15;
    const int l16 = lane >> 4;

    for (int k0 = 0; k0 < EE; k0 += 64) {
#pragma unroll
        for (int p = 0; p < 2; p++) {
            const int row = sr + 32 * p;
            const size_t ga = (size_t)(m0 + row) * EE + k0 + sc;
            const int o = row*64 + dsw;
            *reinterpret_cast<ushort8*>(&sAh[o]) = *reinterpret_cast<const ushort8*>(&Ah[ga]);
            *reinterpret_cast<ushort8*>(&sAl[o]) = *reinterpret_cast<const ushort8*>(&Al[ga]);
        }
#pragma unroll
        for (int p = 0; p < 4; p++) {
            const int row = sr + 32 * p;
            const size_t gb = (size_t)(n0 + row) * EE + k0 + sc;
            const int o = row*64 + dsw;
            *reinterpret_cast<ushort8*>(&sBh[o]) = *reinterpret_cast<const ushort8*>(&Bh[gb]);
            *reinterpret_cast<ushort8*>(&sBl[o]) = *reinterpret_cast<const ushort8*>(&Bl[gb]);
        }
        __syncthreads();
        const int mw = (wave >> 1) * 32;
        const int nw = (wave & 1) * 64;
#pragma unroll
        for (int ks = 0; ks < 2; ks++) {
            const int kc = ks*4 + l16;
            bf16x8 fah[2], fal[2], fbh[4], fbl[4];
#pragma unroll
            for (int i = 0; i < 2; i++) {
                const int ar = mw + 16*i + l15;
                const int ra = ar*64 + ((kc ^ (ar & 7)) << 3);
                fah[i] = *reinterpret_cast<const bf16x8*>(&sAh[ra]);
                fal[i] = *reinterpret_cast<const bf16x8*>(&sAl[ra]);
            }
#pragma unroll
            for (int j = 0; j < 4; j++) {
                const int br = nw + 16*j + l15;
                const int rb = br*64 + ((kc ^ (br & 7)) << 3);
                fbh[j] = *reinterpret_cast<const bf16x8*>(&sBh[rb]);
                fbl[j] = *reinterpret_cast<const bf16x8*>(&sBl[rb]);
            }
#pragma unroll
            for (int i = 0; i < 2; i++)
#pragma unroll
                for (int j = 0; j < 4; j++) {
                    acc[i][j] = __builtin_amdgcn_mfma_f32_16x16x32_bf16(fah[i], fbh[j], acc[i][j], 0, 0, 0);
                    acc[i][j] = __builtin_amdgcn_mfma_f32_16x16x32_bf16(fah[i], fbl[j], acc[i][j], 0, 0, 0);
                    acc[i][j] = __builtin_amdgcn_mfma_f32_16x16x32_bf16(fal[i], fbh[j], acc[i][j], 0, 0, 0);
                }
        }
        __syncthreads();
    }

    const int mw = (wave >> 1) * 32;
    const int nw = (wave & 1) * 64;
#pragma unroll
    for (int j = 0; j < 4; j++) {
        const int col = n0 + nw + 16*j + l15;            // 0..1535
        const int seg = col >> 9;                        // 0=Q 1=K 2=V
        const int c   = col & 511;
        const float bias = (seg == 0 ? bq : (seg == 1 ? bk : bv))[c];
        const float scale = (seg == 0) ? qscale : 1.0f;
        const int h = c >> 6, d = c & 63;
#pragma unroll
        for (int i = 0; i < 2; i++) {
            const int rowb = m0 + mw + 16*i + (l16 << 2);
#pragma unroll
            for (int r4 = 0; r4 < 4; r4++) {
                const int m = rowb + r4;
                const float val = (acc[i][j][r4] + bias) * scale;
                const int bb = m >> 11, s = m & (SS-1);
                const size_t idx = (((size_t)(bb*NH + h)) * SS + s) * DD + d;
                const uint16_t hi = f2bf(val);
                if (seg == 0)      { qh[idx] = hi; ql[idx] = f2bf(val - bf2f(hi)); }
                else if (seg == 1) { kh[idx] = hi; kl[idx] = f2bf(val - bf2f(hi)); }
                else               { vh[idx] = hi; }
            }
        }
    }
}

// ---------------- out-projection, BM=64, swizzled LDS (3 blocks/CU) ----------------
__global__ __launch_bounds__(256, 3)
void gemm_out(const uint16_t* __restrict__ Ah, const uint16_t* __restrict__ Al,
              const uint16_t* __restrict__ Bh, const uint16_t* __restrict__ Bl,
              const float* __restrict__ bo, float* __restrict__ Of)
{
    __shared__ uint16_t sAh[64*64], sAl[64*64], sBh[128*64], sBl[128*64];
    const int t = threadIdx.x;
    const int lane = t & 63;
    const int wave = t >> 6;
    const int m0 = blockIdx.x * 64;
    const int n0 = blockIdx.y * 128;

    f32x4 zero = {0.f, 0.f, 0.f, 0.f};
    f32x4 acc[2][4];
#pragma unroll
    for (int i = 0; i < 2; i++)
#pragma unroll
        for (int j = 0; j < 4; j++) acc[i][j] = zero;

    const int sr = t >> 3;
    const int c8 = t & 7;
    const int sc = c8 * 8;
    const int dsw = ((c8 ^ (sr & 7)) << 3);
    const int l15 = lane & 15;
    const int l16 = lane >> 4;

    for (int k0 = 0; k0 < EE; k0 += 64) {
#pragma unroll
        for (int p = 0; p < 2; p++) {
            const int row = sr + 32 * p;
            const size_t ga = (size_t)(m0 + row) * EE + k0 + sc;
            const int o = row*64 + dsw;
            *reinterpret_cast<ushort8*>(&sAh[o]) = *reinterpret_cast<const ushort8*>(&Ah[ga]);
            *reinterpret_cast<ushort8*>(&sAl[o]) = *reinterpret_cast<const ushort8*>(&Al[ga]);
        }
#pragma unroll
        for (int p = 0; p < 4; p++) {
            const int row = sr + 32 * p;
            const size_t gb = (size_t)(n0 + row) * EE + k0 + sc;
            const int o = row*64 + dsw;
            *reinterpret_cast<ushort8*>(&sBh[o]) = *reinterpret_cast<const ushort8*>(&Bh[gb]);
            *reinterpret_cast<ushort8*>(&sBl[o]) = *reinterpret_cast<const ushort8*>(&Bl[gb]);
        }
        __syncthreads();
        const int mw = (wave >> 1) * 32;
        const int nw = (wave & 1) * 64;
#pragma unroll
        for (int ks = 0; ks < 2; ks++) {
            const int kc = ks*4 + l16;
            bf16x8 fah[2], fal[2], fbh[4], fbl[4];
#pragma unroll
            for (int i = 0; i < 2; i++) {
                const int ar = mw + 16*i + l15;
                const int ra = ar*64 + ((kc ^ (ar & 7)) << 3);
                fah[i] = *reinterpret_cast<const bf16x8*>(&sAh[ra]);
                fal[i] = *reinterpret_cast<const bf16x8*>(&sAl[ra]);
            }
#pragma unroll
            for (int j = 0; j < 4; j++) {
                const int br = nw + 16*j + l15;
                const int rb = br*64 + ((kc ^ (br & 7)) << 3);
                fbh[j] = *reinterpret_cast<const bf16x8*>(&sBh[rb]);
                fbl[j] = *reinterpret_cast<const bf16x8*>(&sBl[rb]);
            }
#pragma unroll
            for (int i = 0; i < 2; i++)
#pragma unroll
                for (int j = 0; j < 4; j++) {
                    acc[i][j] = __builtin_amdgcn_mfma_f32_16x16x32_bf16(fah[i], fbh[j], acc[i][j], 0, 0, 0);
                    acc[i][j] = __builtin_amdgcn_mfma_f32_16x16x32_bf16(fah[i], fbl[j], acc[i][j], 0, 0, 0);
                    acc[i][j] = __builtin_amdgcn_mfma_f32_16x16x32_bf16(fal[i], fbh[j], acc[i][j], 0, 0, 0);
                }
        }
        __syncthreads();
    }

    const int mw = (wave >> 1) * 32;
    const int nw = (wave & 1) * 64;
#pragma unroll
    for (int j = 0; j < 4; j++) {
        const int col = n0 + nw + 16*j + l15;
        const float bv = bo[col];
#pragma unroll
        for (int i = 0; i < 2; i++) {
            const int rowb = m0 + mw + 16*i + (l16 << 2);
#pragma unroll
            for (int r4 = 0; r4 < 4; r4++)
                Of[(size_t)(rowb + r4) * EE + col] = acc[i][j][r4] + bv;
        }
    }
}

// ---------------- fused flash attention (round-11 structure + NT weight stores) ----------------
// Phase 1: single-pass bf16 QK^T -> row sums. Phase 2: 3-pass split scores, weights write, PV.
// ONLY change vs round 13: the 537 MB weights stream uses __builtin_nontemporal_store
// (global_store_dword nt) so it does not evict K/V from L2/L3 between tile re-reads.
__global__ __launch_bounds__(256, 2)
void attn_fused(const uint16_t* __restrict__ Qh, const uint16_t* __restrict__ Ql,
                const uint16_t* __restrict__ Kh, const uint16_t* __restrict__ Kl,
                const uint16_t* __restrict__ Vh,
                float* __restrict__ attn,
                uint16_t* __restrict__ Oh, uint16_t* __restrict__ Ol)
{
    __shared__ __align__(16) uint16_t smem[36864];   // 73728 B -> 2 blocks/CU
    uint16_t* bufA = smem;          // K tile: hi [128][72] @0, lo @+9216 | phase2 W overlay [128][136]
    uint16_t* bufB = smem + 18432;  // phase1 dbuf partner (hi only) | phase2 V^T [64][136]

    const int t = threadIdx.x, lane = t & 63, wave = t >> 6;
    const int qt = blockIdx.x, bh = blockIdx.y;
    const size_t hb = (size_t)bh * SS * DD;
    const uint16_t* kbh = Kh + hb;
    const uint16_t* kbl = Kl + hb;
    const uint16_t* vbs = Vh + hb;

    const int l15 = lane & 15;
    const int l16 = lane >> 4;
    const int sr = t >> 3;        // 0..31
    const int sc = (t & 7) * 8;   // 0..56

    // ---- K staging regs (global->reg->LDS) ----
    ushort8 krh[4], krl[4];
    auto kload_hi = [&](int kt) {
#pragma unroll
        for (int p = 0; p < 4; p++) {
            const size_t g = (size_t)(kt*128 + sr + 32*p) * DD + sc;
            krh[p] = *reinterpret_cast<const ushort8*>(&kbh[g]);
        }
    };
    auto kwrite_hi = [&](uint16_t* buf) {
#pragma unroll
        for (int p = 0; p < 4; p++) {
            const int o = (sr + 32*p)*LDP + sc;
            *reinterpret_cast<ushort8*>(&buf[o]) = krh[p];
        }
    };
    auto kload = [&](int kt) {
#pragma unroll
        for (int p = 0; p < 4; p++) {
            const size_t g = (size_t)(kt*128 + sr + 32*p) * DD + sc;
            krh[p] = *reinterpret_cast<const ushort8*>(&kbh[g]);
            krl[p] = *reinterpret_cast<const ushort8*>(&kbl[g]);
        }
    };
    auto kwrite = [&](uint16_t* buf) {
#pragma unroll
        for (int p = 0; p < 4; p++) {
            const int o = (sr + 32*p)*LDP + sc;
            *reinterpret_cast<ushort8*>(&buf[o]) = krh[p];
            *reinterpret_cast<ushort8*>(&buf[9216 + o]) = krl[p];
        }
    };

    // ---- Q fragments in registers (persistent) ----
    bf16x8 qfh[2][2], qfl[2][2];
#pragma unroll
    for (int i = 0; i < 2; i++)
#pragma unroll
        for (int ks = 0; ks < 2; ks++) {
            const size_t qa = hb + (size_t)(qt*128 + wave*32 + 16*i + l15) * DD + ks*32 + l16*8;
            qfh[i][ks] = *reinterpret_cast<const bf16x8*>(&Qh[qa]);
            qfl[i][ks] = *reinterpret_cast<const bf16x8*>(&Ql[qa]);
        }

    f32x4 zero = {0.f, 0.f, 0.f, 0.f};
    f32x4 lsum[2] = {zero, zero};

    // ================= phase 1: row sums of exp2(scores), single-pass bf16 =================
    kload_hi(0);
#pragma unroll 1
    for (int kt = 0; kt < 16; kt++) {
        uint16_t* buf = (kt & 1) ? bufB : bufA;
        kwrite_hi(buf);
        if (kt < 15) kload_hi(kt + 1);
        __syncthreads();

        f32x4 accs[2][8];
#pragma unroll
        for (int i = 0; i < 2; i++)
#pragma unroll
            for (int j = 0; j < 8; j++) accs[i][j] = zero;

#pragma unroll
        for (int ks = 0; ks < 2; ks++) {
            const int kk = ks*32 + l16*8;
#pragma unroll
            for (int j = 0; j < 8; j++) {
                const int rb = (16*j + l15) * LDP + kk;
                bf16x8 fbh = *reinterpret_cast<const bf16x8*>(&buf[rb]);
#pragma unroll
                for (int i = 0; i < 2; i++)
                    accs[i][j] = __builtin_amdgcn_mfma_f32_16x16x32_bf16(qfh[i][ks], fbh, accs[i][j], 0, 0, 0);
            }
        }

#pragma unroll
        for (int i = 0; i < 2; i++)
#pragma unroll
            for (int j = 0; j < 8; j++)
#pragma unroll
                for (int r = 0; r < 4; r++)
                    lsum[i][r] += __builtin_amdgcn_exp2f(accs[i][j][r]);
    }

    // finalize: reduce over the 16-lane row group, invert
    f32x4 iv[2];
#pragma unroll
    for (int i = 0; i < 2; i++)
#pragma unroll
        for (int r = 0; r < 4; r++) {
            float s = lsum[i][r];
#pragma unroll
            for (int o = 1; o < 16; o <<= 1) s += __shfl_xor(s, o);
            iv[i][r] = 1.0f / s;
        }

    f32x4 acco[2][4];
#pragma unroll
    for (int i = 0; i < 2; i++)
#pragma unroll
        for (int j = 0; j < 4; j++) acco[i][j] = zero;

    float* wbase = attn + ((size_t)bh * SS + qt*128) * SS;

    // ---- V staging: pair-packed b32 writes (conflict-free) ----
    const int pk = t & 63;             // k-pair index (k = 2pk, 2pk+1)
    const int dbase = (t >> 6) * 16;   // d-quarter
    ushort8 vr[2][2];
    auto vload = [&](int kt) {
#pragma unroll
        for (int u = 0; u < 2; u++)
#pragma unroll
            for (int s = 0; s < 2; s++)
                vr[u][s] = *reinterpret_cast<const ushort8*>(
                    &vbs[(size_t)(kt*128 + 2*pk + s) * DD + dbase + u*8]);
    };
    auto vwrite = [&](uint16_t* vbufp) {
#pragma unroll
        for (int u = 0; u < 2; u++)
#pragma unroll
            for (int e = 0; e < 8; e++) {
                const int d = dbase + u*8 + e;
                const uint32_t pack = (uint32_t)(unsigned short)vr[u][0][e]
                                    | ((uint32_t)(unsigned short)vr[u][1][e] << 16);
                *reinterpret_cast<uint32_t*>(&vbufp[d*LDW + 2*pk]) = pack;
            }
    };

    __syncthreads();   // phase boundary: all phase-1 reads of bufB done

    // ================= phase 2: recompute (3-pass), write weights, PV =================
    kload(0); vload(0);
#pragma unroll 1
    for (int kt = 0; kt < 16; kt++) {
        kwrite(bufA);
        vwrite(bufB);
        __syncthreads();                       // bar1: K/V staged

        f32x4 accs[2][8];
#pragma unroll
        for (int i = 0; i < 2; i++)
#pragma unroll
            for (int j = 0; j < 8; j++) accs[i][j] = zero;
#pragma unroll
        for (int ks = 0; ks < 2; ks++) {
            const int kk = ks*32 + l16*8;
#pragma unroll
            for (int j = 0; j < 8; j++) {
                const int rb = (16*j + l15) * LDP + kk;
                bf16x8 fbh = *reinterpret_cast<const bf16x8*>(&bufA[rb]);
                bf16x8 fbl = *reinterpret_cast<const bf16x8*>(&bufA[9216 + rb]);
#pragma unroll
                for (int i = 0; i < 2; i++) {
                    accs[i][j] = __builtin_amdgcn_mfma_f32_16x16x32_bf16(qfh[i][ks], fbh, accs[i][j], 0, 0, 0);
                    accs[i][j] = __builtin_amdgcn_mfma_f32_16x16x32_bf16(qfh[i][ks], fbl, accs[i][j], 0, 0, 0);
                    accs[i][j] = __builtin_amdgcn_mfma_f32_16x16x32_bf16(qfl[i][ks], fbh, accs[i][j], 0, 0, 0);
                }
            }
        }

        // prefetch next tile's K/V while VALU works (T14)
        if (kt < 15) { kload(kt + 1); vload(kt + 1); }

        // normalize: w = exp2(s) * inv_sum (no max shift)
#pragma unroll
        for (int i = 0; i < 2; i++)
#pragma unroll
            for (int j = 0; j < 8; j++)
#pragma unroll
                for (int r = 0; r < 4; r++)
                    accs[i][j][r] = __builtin_amdgcn_exp2f(accs[i][j][r]) * iv[i][r];

        __syncthreads();                       // bar2: all K reads done

        // W bf16 -> bufA overlay
#pragma unroll
        for (int i = 0; i < 2; i++)
#pragma unroll
            for (int r = 0; r < 4; r++) {
                const int row = wave*32 + 16*i + l16*4 + r;
#pragma unroll
                for (int j = 0; j < 8; j++)
                    bufA[row*LDW + l15 + 16*j] = f2bf(accs[i][j][r]);
            }
        __syncthreads();                       // bar3: W/V visible

        // weight stores issued HERE, NON-TEMPORAL: PV MFMA below hides the store
        // latency, and the nt flag keeps the 537 MB stream from evicting K/V in L2/L3.
#pragma unroll
        for (int i = 0; i < 2; i++)
#pragma unroll
            for (int r = 0; r < 4; r++) {
                const int row = wave*32 + 16*i + l16*4 + r;
                float* wout = wbase + (size_t)row * SS + kt*128 + l15;
#pragma unroll
                for (int j = 0; j < 8; j++)
                    __builtin_nontemporal_store(accs[i][j][r], &wout[16*j]);
            }

        // PV: O += W @ V
#pragma unroll
        for (int ks = 0; ks < 4; ks++) {
            const int kk = ks*32 + l16*8;
            bf16x8 wa[2], vbf[4];
#pragma unroll
            for (int i = 0; i < 2; i++)
                wa[i] = *reinterpret_cast<const bf16x8*>(&bufA[(wave*32 + 16*i + l15)*LDW + kk]);
#pragma unroll
            for (int j = 0; j < 4; j++)
                vbf[j] = *reinterpret_cast<const bf16x8*>(&bufB[(16*j + l15)*LDW + kk]);
#pragma unroll
            for (int i = 0; i < 2; i++)
#pragma unroll
                for (int j = 0; j < 4; j++)
                    acco[i][j] = __builtin_amdgcn_mfma_f32_16x16x32_bf16(wa[i], vbf[j], acco[i][j], 0, 0, 0);
        }
        __syncthreads();                       // bar4: PV reads + stores drained
    }

    // epilogue: attn_output split-bf16 into [b, s, h*64+d]
    const int b = bh >> 3, h = bh & 7;
#pragma unroll
    for (int i = 0; i < 2; i++)
#pragma unroll
        for (int j = 0; j < 4; j++)
#pragma unroll
            for (int r4 = 0; r4 < 4; r4++) {
                const int srow = qt*128 + wave*32 + 16*i + (l16 << 2) + r4;
                const int col = h*64 + 16*j + l15;
                const size_t idx = ((size_t)b * SS + srow) * (size_t)EE + col;
                const float val = acco[i][j][r4];
                const uint16_t hh = f2bf(val);
                Oh[idx] = hh;
                Ol[idx] = f2bf(val - bf2f(hh));
            }
}

extern "C" void kernel_launch(void* const* d_in, const int* in_sizes, int n_in,
                              void* d_out, int out_size, void* d_ws, size_t ws_size,
                              hipStream_t stream)
{
    const float* x  = (const float*)d_in[0];
    const float* Wq = (const float*)d_in[1];
    const float* bq = (const float*)d_in[2];
    const float* Wk = (const float*)d_in[3];
    const float* bk = (const float*)d_in[4];
    const float* Wv = (const float*)d_in[5];
    const float* bv = (const float*)d_in[6];
    const float* Wo = (const float*)d_in[7];
    const float* bo = (const float*)d_in[8];

    float* outF = (float*)d_out;
    float* attn = outF + (size_t)MM * EE;   // output 1 region (normalized weights)

    const size_t NXE = (size_t)MM * EE;     // 4,194,304
    const size_t NW  = (size_t)EE * EE;     // 262,144
    uint16_t* p = (uint16_t*)d_ws;
    uint16_t* xh    = p;          p += NXE;
    uint16_t* xl    = p;          p += NXE;
    uint16_t* wqkvh = p;          p += 3*NW;
    uint16_t* wqkvl = p;          p += 3*NW;
    uint16_t* woh   = p;          p += NW;
    uint16_t* wol   = p;          p += NW;
    uint16_t* qh    = p;          p += NXE;
    uint16_t* ql    = p;          p += NXE;
    uint16_t* kh    = p;          p += NXE;
    uint16_t* kl    = p;          p += NXE;
    uint16_t* vh    = p;          p += NXE;
    uint16_t* ah    = p;          p += NXE;
    uint16_t* al    = p;          p += NXE;

    split_all<<<4096 + 4*256, 256, 0, stream>>>(x, Wq, Wk, Wv, Wo,
                                                xh, xl, wqkvh, wqkvl, woh, wol);

    // Q scaled by 0.125*log2(e): scores land in log2 units -> softmax uses exp2 directly
    const float qscale = 0.125f * 1.44269504088896340736f;
    gemm_qkv<<<dim3(MM/64, (3*EE)/128), 256, 0, stream>>>(
        xh, xl, wqkvh, wqkvl, bq, bk, bv, qscale, qh, ql, kh, kl, vh);

    attn_fused<<<dim3(SS/128, NB*NH), 256, 0, stream>>>(qh, ql, kh, kl, vh, attn, ah, al);

    gemm_out<<<dim3(MM/64, EE/128), 256, 0, stream>>>(ah, al, woh, wol, bo, outF);
}